// Round 1
// 872.686 us; speedup vs baseline: 1.9109x; 1.9109x over previous
//
#include <hip/hip_runtime.h>
#include <hip/hip_bf16.h>
#include <stdint.h>

// Problem constants
constexpr int B_ = 32, N_ = 4096, D_ = 256, NH_ = 4, DH_ = 64, NS_ = 8;
constexpr float EPS_ = 1e-8f;

typedef unsigned short u16;
typedef __attribute__((ext_vector_type(8))) short bf16x8;   // 8 bf16 (4 VGPRs)
typedef __attribute__((ext_vector_type(4))) float f32x4;    // MFMA accumulator

__device__ inline u16 f2bf(float f) {
  unsigned u = __float_as_uint(f);
  unsigned r = u + 0x7FFFu + ((u >> 16) & 1u);   // RNE
  return (u16)(r >> 16);
}
__device__ inline float bf2f(u16 u) {
  return __uint_as_float(((unsigned)u) << 16);
}

// Giles single-precision erfinv — same coefficients XLA uses for f32 erf_inv
__device__ inline float erfinv_f(float x) {
  float w = -logf((1.0f - x) * (1.0f + x));
  float p;
  if (w < 5.0f) {
    w = w - 2.5f;
    p = 2.81022636e-08f;
    p = 3.43273939e-07f + p * w;
    p = -3.5233877e-06f + p * w;
    p = -4.39150654e-06f + p * w;
    p = 0.00021858087f + p * w;
    p = -0.00125372503f + p * w;
    p = -0.00417768164f + p * w;
    p = 0.246640727f + p * w;
    p = 1.50140941f + p * w;
  } else {
    w = sqrtf(w) - 3.0f;
    p = -0.000200214257f;
    p = 0.000100950558f + p * w;
    p = 0.00134934322f + p * w;
    p = -0.00367342844f + p * w;
    p = 0.00573950773f + p * w;
    p = -0.0076224613f + p * w;
    p = 0.00943887047f + p * w;
    p = 1.00167406f + p * w;
    p = 2.83297682f + p * w;
  }
  return p * x;
}

// Threefry-2x32, 20 rounds (JAX PRNG), key (0, 42)
__device__ inline void threefry(unsigned k0, unsigned k1, unsigned& x0, unsigned& x1) {
  unsigned ks2 = k0 ^ k1 ^ 0x1BD11BDAu;
  x0 += k0; x1 += k1;
#define TF_R(r) { x0 += x1; x1 = (x1 << (r)) | (x1 >> (32 - (r))); x1 ^= x0; }
  TF_R(13) TF_R(15) TF_R(26) TF_R(6)
  x0 += k1; x1 += ks2 + 1u;
  TF_R(17) TF_R(29) TF_R(16) TF_R(24)
  x0 += ks2; x1 += k0 + 2u;
  TF_R(13) TF_R(15) TF_R(26) TF_R(6)
  x0 += k0; x1 += k1 + 3u;
  TF_R(17) TF_R(29) TF_R(16) TF_R(24)
  x0 += k1; x1 += ks2 + 4u;
  TF_R(13) TF_R(15) TF_R(26) TF_R(6)
  x0 += ks2; x1 += k0 + 5u;
#undef TF_R
}

__device__ inline float bits_to_normal(unsigned bits) {
  float f = __uint_as_float((bits >> 9) | 0x3F800000u) - 1.0f;
  const float lo = -0.99999994f;
  const float span = 2.0f;
  float u = fmaxf(lo, f * span + lo);
  return 1.41421356f * erfinv_f(u);
}

// ---------- kernel 1: slot init — partitionable threefry (jax >= 0.4.36 default) ----------
__global__ __launch_bounds__(256) void k_slots_init(const float* __restrict__ mu,
                                                    const float* __restrict__ logsigma,
                                                    float* __restrict__ slots) {
  unsigned e = blockIdx.x * 256u + threadIdx.x;   // [0, 65536)
  unsigned x0 = 0u, x1 = e;
  threefry(0u, 42u, x0, x1);
  unsigned bits = x0 ^ x1;
  float n = bits_to_normal(bits);
  int d = e & 255;
  slots[e] = mu[d] + expf(logsigma[d]) * n;
}

// ---------- kernel 2: q = LN(slots) @ Wq, pre-scaled by DH^-0.5 ----------
__global__ __launch_bounds__(256) void k_qproj(const float* __restrict__ slots,
                                               const float* __restrict__ ln_w,
                                               const float* __restrict__ ln_b,
                                               const float* __restrict__ Wq,
                                               float* __restrict__ qout) {
  __shared__ float sn[256];
  __shared__ float redA[4], redB[4];
  int row = blockIdx.x, t = threadIdx.x;
  float x = slots[row * 256 + t];
  float s = x, s2 = x * x;
#pragma unroll
  for (int off = 32; off; off >>= 1) { s += __shfl_xor(s, off); s2 += __shfl_xor(s2, off); }
  if ((t & 63) == 0) { redA[t >> 6] = s; redB[t >> 6] = s2; }
  __syncthreads();
  float ts = redA[0] + redA[1] + redA[2] + redA[3];
  float ts2 = redB[0] + redB[1] + redB[2] + redB[3];
  float m = ts * (1.0f / 256.0f);
  float var = ts2 * (1.0f / 256.0f) - m * m;
  float rstd = rsqrtf(var + 1e-5f);
  sn[t] = (x - m) * rstd * ln_w[t] + ln_b[t];
  __syncthreads();
  float a = 0.0f;
  for (int k = 0; k < 256; ++k) a += sn[k] * Wq[k * 256 + t];
  qout[row * 256 + t] = a * 0.125f;
}

// ---------- kernel W: transpose Wk/Wv -> bf16 Wt[512][256] (B^T layout for MFMA) ----------
// Row n of Wt (n < 256 -> Wk col n; n >= 256 -> Wv col n-256), contiguous in k.
__global__ __launch_bounds__(256) void k_wt(const float* __restrict__ Wk,
                                            const float* __restrict__ Wv,
                                            u16* __restrict__ Wt) {
  int n = blockIdx.x;                      // 0..255 (column of W)
  int t = threadIdx.x;                     // k
  const float* src = blockIdx.y ? Wv : Wk;
  Wt[((blockIdx.y * 256 + n) << 8) + t] = f2bf(src[t * 256 + n]);
}

// ---------- kernel 3a (fast path): LN(inputs) + K/V projection via MFMA ----------
// Grid (2048 M-blocks, 2 halves: y=0 -> Wk -> kbuf, y=1 -> Wv -> vbuf).
// Block = 256 threads (4 waves). Block tile 64 rows x 256 cols; wave tile 64x64.
// LDS: padded bf16 A tile [64][264] = 33 KB (row-bank rotation, ~2-way = free).
__global__ __launch_bounds__(256, 4) void k_proj_mfma(
    const float* __restrict__ in,
    const float* __restrict__ ln_w, const float* __restrict__ ln_b,
    const u16* __restrict__ Wt,
    u16* __restrict__ kbuf, u16* __restrict__ vbuf) {
  constexpr int LDA = 264;                       // 256 + 8 bf16 pad (16 B, keeps 16 B align)
  __shared__ __align__(16) u16 Asm[64 * LDA];    // 33792 B
  int t = threadIdx.x;
  int wave = t >> 6, lane = t & 63;
  int q = lane >> 4, r = lane & 15;
  long row0 = (long)blockIdx.x * 64;
  int half = blockIdx.y;                         // 0=K, 1=V

  // ---- Phase 1: LN of 64 rows -> bf16 LDS A-tile (16 rows per wave) ----
  float4 lw = ((const float4*)ln_w)[lane];
  float4 lb = ((const float4*)ln_b)[lane];
#pragma unroll 4
  for (int j = 0; j < 16; ++j) {
    int rr = wave * 16 + j;
    float4 v = ((const float4*)(in + (row0 + rr) * D_))[lane];
    float s = v.x + v.y + v.z + v.w;
    float s2 = v.x * v.x + v.y * v.y + v.z * v.z + v.w * v.w;
#pragma unroll
    for (int off = 32; off; off >>= 1) { s += __shfl_xor(s, off); s2 += __shfl_xor(s2, off); }
    float m = s * (1.0f / 256.0f);
    float var = s2 * (1.0f / 256.0f) - m * m;
    float rstd = rsqrtf(var + 1e-5f);
    unsigned p0 = (unsigned)f2bf((v.x - m) * rstd * lw.x + lb.x)
                | ((unsigned)f2bf((v.y - m) * rstd * lw.y + lb.y) << 16);
    unsigned p1 = (unsigned)f2bf((v.z - m) * rstd * lw.z + lb.z)
                | ((unsigned)f2bf((v.w - m) * rstd * lw.w + lb.w) << 16);
    *(uint2*)&Asm[rr * LDA + lane * 4] = make_uint2(p0, p1);
  }
  __syncthreads();

  // ---- Phase 2: K-loop, 8 steps of K=32; wave computes 64x64 via 4x4 16x16 frags ----
  f32x4 acc[4][4];
#pragma unroll
  for (int mf = 0; mf < 4; ++mf)
#pragma unroll
    for (int nf = 0; nf < 4; ++nf) acc[mf][nf] = (f32x4)0.0f;

  const u16* wt_base = Wt + (long)(half * 256 + wave * 64) * 256;
#pragma unroll 1
  for (int k0 = 0; k0 < 256; k0 += 32) {
    bf16x8 a[4], b[4];
#pragma unroll
    for (int mf = 0; mf < 4; ++mf)
      a[mf] = *(const bf16x8*)&Asm[(mf * 16 + r) * LDA + k0 + q * 8];
#pragma unroll
    for (int nf = 0; nf < 4; ++nf)
      b[nf] = *(const bf16x8*)&wt_base[(nf * 16 + r) * 256 + k0 + q * 8];
#pragma unroll
    for (int mf = 0; mf < 4; ++mf)
#pragma unroll
      for (int nf = 0; nf < 4; ++nf)
        acc[mf][nf] = __builtin_amdgcn_mfma_f32_16x16x32_bf16(a[mf], b[nf], acc[mf][nf], 0, 0, 0);
  }

  // ---- Epilogue: restage through LDS for coalesced 16 B bf16 stores ----
  __syncthreads();                               // all waves done reading A-tile
  u16* st = Asm + wave * 4096;                   // per-wave u16[64][64] region (8 KB)
#pragma unroll
  for (int mf = 0; mf < 4; ++mf)
#pragma unroll
    for (int nf = 0; nf < 4; ++nf)
#pragma unroll
      for (int rr = 0; rr < 4; ++rr)
        st[(mf * 16 + q * 4 + rr) * 64 + nf * 16 + r] = f2bf(acc[mf][nf][rr]);
  // same-wave LDS RAW: compiler inserts lgkmcnt before the reads below
  u16* outp = (half == 0) ? kbuf : vbuf;
  int colbase = wave * 64;
#pragma unroll
  for (int p = 0; p < 8; ++p) {
    int rr = p * 8 + (lane >> 3);
    int cc = (lane & 7) * 8;
    uint4 val = *(const uint4*)&st[rr * 64 + cc];
    *(uint4*)&outp[(row0 + rr) * 256 + colbase + cc] = val;
  }
}

// ---------- kernel 3b (fast path): streaming attention over cached bf16 K/V ----------
__global__ __launch_bounds__(256) void k_attn(
    const float* __restrict__ qbuf,
    const u16* __restrict__ kbuf, const u16* __restrict__ vbuf,
    float* __restrict__ U, float* __restrict__ S) {
  __shared__ float redS[2048];
  __shared__ float sredS[32];
  int b = blockIdx.y, chunk = blockIdx.x;
  int t = threadIdx.x;
  int wave = t >> 6, lane = t & 63;

  for (int e = t; e < 2048; e += 256) redS[e] = 0.0f;
  if (t < 32) sredS[t] = 0.0f;

  float qv[8][4];
#pragma unroll
  for (int i = 0; i < 8; ++i) {
    float4 qq = *(const float4*)(qbuf + ((long)(b * 8 + i)) * 256 + lane * 4);
    qv[i][0] = qq.x; qv[i][1] = qq.y; qv[i][2] = qq.z; qv[i][3] = qq.w;
  }
  float acc[8][4];
  float sacc[8];
#pragma unroll
  for (int i = 0; i < 8; ++i) {
    sacc[i] = 0.0f;
    acc[i][0] = acc[i][1] = acc[i][2] = acc[i][3] = 0.0f;
  }
  __syncthreads();

  long jbase = (long)b * N_ + chunk * 128;
  for (int jj = wave; jj < 128; jj += 4) {
    long off = (jbase + jj) * 256 + lane * 4;
    ushort4 k4 = *(const ushort4*)(kbuf + off);
    ushort4 v4 = *(const ushort4*)(vbuf + off);
    float k0 = bf2f(k4.x), k1 = bf2f(k4.y), k2 = bf2f(k4.z), k3 = bf2f(k4.w);

    float d[8];
#pragma unroll
    for (int i = 0; i < 8; ++i)
      d[i] = qv[i][0] * k0 + qv[i][1] * k1 + qv[i][2] * k2 + qv[i][3] * k3;
#pragma unroll
    for (int off2 = 1; off2 < 16; off2 <<= 1) {
#pragma unroll
      for (int i = 0; i < 8; ++i) d[i] += __shfl_xor(d[i], off2);
    }
    float mx = d[0];
#pragma unroll
    for (int i = 1; i < 8; ++i) mx = fmaxf(mx, d[i]);
    float e[8], sum = 0.0f;
#pragma unroll
    for (int i = 0; i < 8; ++i) { e[i] = expf(d[i] - mx); sum += e[i]; }
    float inv = 1.0f / sum;

    float v0 = bf2f(v4.x), v1 = bf2f(v4.y), v2 = bf2f(v4.z), v3 = bf2f(v4.w);
#pragma unroll
    for (int i = 0; i < 8; ++i) {
      float a = e[i] * inv + EPS_;
      sacc[i] += a;
      acc[i][0] += a * v0; acc[i][1] += a * v1; acc[i][2] += a * v2; acc[i][3] += a * v3;
    }
  }

#pragma unroll
  for (int i = 0; i < 8; ++i) {
    atomicAdd(&redS[i * 256 + lane * 4 + 0], acc[i][0]);
    atomicAdd(&redS[i * 256 + lane * 4 + 1], acc[i][1]);
    atomicAdd(&redS[i * 256 + lane * 4 + 2], acc[i][2]);
    atomicAdd(&redS[i * 256 + lane * 4 + 3], acc[i][3]);
  }
  if ((lane & 15) == 0) {
    int h = lane >> 4;
#pragma unroll
    for (int i = 0; i < 8; ++i) atomicAdd(&sredS[i * 4 + h], sacc[i]);
  }
  __syncthreads();

  for (int e = t; e < 2048; e += 256)
    atomicAdd(&U[((long)b * 8 + (e >> 8)) * 256 + (e & 255)], redS[e]);
  if (t < 32) atomicAdd(&S[b * 32 + t], sredS[t]);
}

// ---------- kernel 3-fallback: fused LN+proj+attention (96 KB LDS) ----------
__global__ __launch_bounds__(256) void k_fused_attn(
    const float* __restrict__ in,
    const float* __restrict__ ln_w, const float* __restrict__ ln_b,
    const float* __restrict__ Wk, const float* __restrict__ Wv,
    const float* __restrict__ qbuf,
    float* __restrict__ U, float* __restrict__ S) {
  __shared__ __align__(16) float ldsf[24576];
  float* xs = ldsf;
  float* kf = ldsf + 8192;
  float* vf = ldsf + 16384;
  float* qs    = ldsf;
  float* redS  = ldsf + 2048;
  float* sredS = ldsf + 4096;

  int b = blockIdx.y, chunk = blockIdx.x;
  int t = threadIdx.x;
  int wave = t >> 6, lane = t & 63;
  long row0 = (long)b * N_ + (long)chunk * 32;

  for (int j = 0; j < 8; ++j) {
    int r = wave * 8 + j;
    const float4* rp = (const float4*)(in + (row0 + r) * D_);
    float4 v = rp[lane];
    float s = v.x + v.y + v.z + v.w;
    float s2 = v.x * v.x + v.y * v.y + v.z * v.z + v.w * v.w;
#pragma unroll
    for (int off = 32; off; off >>= 1) { s += __shfl_xor(s, off); s2 += __shfl_xor(s2, off); }
    float m = s * (1.0f / 256.0f);
    float var = s2 * (1.0f / 256.0f) - m * m;
    float rstd = rsqrtf(var + 1e-5f);
    int c = lane * 4;
    xs[r * 256 + c + 0] = (v.x - m) * rstd * ln_w[c + 0] + ln_b[c + 0];
    xs[r * 256 + c + 1] = (v.y - m) * rstd * ln_w[c + 1] + ln_b[c + 1];
    xs[r * 256 + c + 2] = (v.z - m) * rstd * ln_w[c + 2] + ln_b[c + 2];
    xs[r * 256 + c + 3] = (v.w - m) * rstd * ln_w[c + 3] + ln_b[c + 3];
  }
  __syncthreads();

  {
    int tx = t & 31, ty = t >> 5;
    const float* W = (tx < 16) ? Wk : Wv;
    float* obf = (tx < 16) ? kf : vf;
    int col0 = (tx & 15) * 16;
    float acc2[4][16];
#pragma unroll
    for (int r = 0; r < 4; ++r)
#pragma unroll
      for (int c = 0; c < 16; ++c) acc2[r][c] = 0.0f;

    for (int k = 0; k < 256; ++k) {
      const float4* wp = (const float4*)(W + k * 256 + col0);
      float4 w0 = wp[0], w1 = wp[1], w2 = wp[2], w3 = wp[3];
#pragma unroll
      for (int r = 0; r < 4; ++r) {
        float x = xs[(ty * 4 + r) * 256 + k];
        acc2[r][0]  += x * w0.x; acc2[r][1]  += x * w0.y; acc2[r][2]  += x * w0.z; acc2[r][3]  += x * w0.w;
        acc2[r][4]  += x * w1.x; acc2[r][5]  += x * w1.y; acc2[r][6]  += x * w1.z; acc2[r][7]  += x * w1.w;
        acc2[r][8]  += x * w2.x; acc2[r][9]  += x * w2.y; acc2[r][10] += x * w2.z; acc2[r][11] += x * w2.w;
        acc2[r][12] += x * w3.x; acc2[r][13] += x * w3.y; acc2[r][14] += x * w3.z; acc2[r][15] += x * w3.w;
      }
    }
#pragma unroll
    for (int r = 0; r < 4; ++r) {
      float4* dst = (float4*)&obf[(ty * 4 + r) * 256 + col0];
      dst[0] = make_float4(acc2[r][0],  acc2[r][1],  acc2[r][2],  acc2[r][3]);
      dst[1] = make_float4(acc2[r][4],  acc2[r][5],  acc2[r][6],  acc2[r][7]);
      dst[2] = make_float4(acc2[r][8],  acc2[r][9],  acc2[r][10], acc2[r][11]);
      dst[3] = make_float4(acc2[r][12], acc2[r][13], acc2[r][14], acc2[r][15]);
    }
  }
  __syncthreads();

#pragma unroll
  for (int i = 0; i < 8; ++i) qs[i * 256 + t] = qbuf[((long)b * 8 + i) * 256 + t];
  for (int e = t; e < 2048; e += 256) redS[e] = 0.0f;
  if (t < 32) sredS[t] = 0.0f;
  __syncthreads();

  float qv[8][4];
#pragma unroll
  for (int i = 0; i < 8; ++i) {
    float4 qq = *(const float4*)&qs[i * 256 + lane * 4];
    qv[i][0] = qq.x; qv[i][1] = qq.y; qv[i][2] = qq.z; qv[i][3] = qq.w;
  }
  float acc[8][4];
  float sacc[8];
#pragma unroll
  for (int i = 0; i < 8; ++i) {
    sacc[i] = 0.0f;
    acc[i][0] = acc[i][1] = acc[i][2] = acc[i][3] = 0.0f;
  }

  for (int jj = wave; jj < 32; jj += 4) {
    float4 k4 = *(const float4*)&kf[jj * 256 + lane * 4];
    float d[8];
#pragma unroll
    for (int i = 0; i < 8; ++i)
      d[i] = qv[i][0] * k4.x + qv[i][1] * k4.y + qv[i][2] * k4.z + qv[i][3] * k4.w;
#pragma unroll
    for (int off2 = 1; off2 < 16; off2 <<= 1) {
#pragma unroll
      for (int i = 0; i < 8; ++i) d[i] += __shfl_xor(d[i], off2);
    }
    float mx = d[0];
#pragma unroll
    for (int i = 1; i < 8; ++i) mx = fmaxf(mx, d[i]);
    float e[8], sum = 0.0f;
#pragma unroll
    for (int i = 0; i < 8; ++i) { e[i] = expf(d[i] - mx); sum += e[i]; }
    float inv = 1.0f / sum;

    float4 v4 = *(const float4*)&vf[jj * 256 + lane * 4];
#pragma unroll
    for (int i = 0; i < 8; ++i) {
      float a = e[i] * inv + EPS_;
      sacc[i] += a;
      acc[i][0] += a * v4.x; acc[i][1] += a * v4.y; acc[i][2] += a * v4.z; acc[i][3] += a * v4.w;
    }
  }

#pragma unroll
  for (int i = 0; i < 8; ++i) {
    atomicAdd(&redS[i * 256 + lane * 4 + 0], acc[i][0]);
    atomicAdd(&redS[i * 256 + lane * 4 + 1], acc[i][1]);
    atomicAdd(&redS[i * 256 + lane * 4 + 2], acc[i][2]);
    atomicAdd(&redS[i * 256 + lane * 4 + 3], acc[i][3]);
  }
  if ((lane & 15) == 0) {
    int h = lane >> 4;
#pragma unroll
    for (int i = 0; i < 8; ++i) atomicAdd(&sredS[i * 4 + h], sacc[i]);
  }
  __syncthreads();

  for (int e = t; e < 2048; e += 256)
    atomicAdd(&U[((long)b * 8 + (e >> 8)) * 256 + (e & 255)], redS[e]);
  if (t < 32) atomicAdd(&S[b * 32 + t], sredS[t]);
}

// ---------- kernel 4: normalize + Wc + GRU + LN + MLP ----------
__global__ __launch_bounds__(256) void k_slot_update(
    const float* __restrict__ U, const float* __restrict__ S,
    float* __restrict__ slots,
    const float* __restrict__ Wc,
    const float* __restrict__ w_ih, const float* __restrict__ w_hh,
    const float* __restrict__ b_ih, const float* __restrict__ b_hh,
    const float* __restrict__ ln_m_w, const float* __restrict__ ln_m_b,
    const float* __restrict__ w1, const float* __restrict__ b1,
    const float* __restrict__ w2, const float* __restrict__ b2,
    float* __restrict__ out_final, int write_out) {
  __shared__ float un[256], upd[256], hprev[256], mbuf[256], hid[128];
  __shared__ float redA[4], redB[4];
  int row = blockIdx.x, t = threadIdx.x;

  float denom = S[row * 4 + (t >> 6)];
  un[t] = U[(long)row * 256 + t] / denom;
  float hp = slots[(long)row * 256 + t];
  hprev[t] = hp;
  __syncthreads();

  float a = 0.0f;
  for (int k = 0; k < 256; ++k) a += un[k] * Wc[k * 256 + t];
  upd[t] = a;
  __syncthreads();

  float gxr = b_ih[t], gxz = b_ih[256 + t], gxn = b_ih[512 + t];
  float ghr = b_hh[t], ghz = b_hh[256 + t], ghn = b_hh[512 + t];
  const float4* u4 = (const float4*)upd;
  const float4* h4 = (const float4*)hprev;
  const float4* wr = (const float4*)(w_ih + (long)t * 256);
  const float4* wz = (const float4*)(w_ih + (long)(256 + t) * 256);
  const float4* wn = (const float4*)(w_ih + (long)(512 + t) * 256);
  const float4* vr = (const float4*)(w_hh + (long)t * 256);
  const float4* vz = (const float4*)(w_hh + (long)(256 + t) * 256);
  const float4* vn = (const float4*)(w_hh + (long)(512 + t) * 256);
  for (int k = 0; k < 64; ++k) {
    float4 uu = u4[k], hh = h4[k], w;
    w = wr[k]; gxr += uu.x * w.x + uu.y * w.y + uu.z * w.z + uu.w * w.w;
    w = wz[k]; gxz += uu.x * w.x + uu.y * w.y + uu.z * w.z + uu.w * w.w;
    w = wn[k]; gxn += uu.x * w.x + uu.y * w.y + uu.z * w.z + uu.w * w.w;
    w = vr[k]; ghr += hh.x * w.x + hh.y * w.y + hh.z * w.z + hh.w * w.w;
    w = vz[k]; ghz += hh.x * w.x + hh.y * w.y + hh.z * w.z + hh.w * w.w;
    w = vn[k]; ghn += hh.x * w.x + hh.y * w.y + hh.z * w.z + hh.w * w.w;
  }
  float r = 1.0f / (1.0f + expf(-(gxr + ghr)));
  float z = 1.0f / (1.0f + expf(-(gxz + ghz)));
  float ng = tanhf(gxn + r * ghn);
  float sv = (1.0f - z) * ng + z * hp;

  float s1 = sv, s2v = sv * sv;
#pragma unroll
  for (int off = 32; off; off >>= 1) { s1 += __shfl_xor(s1, off); s2v += __shfl_xor(s2v, off); }
  if ((t & 63) == 0) { redA[t >> 6] = s1; redB[t >> 6] = s2v; }
  __syncthreads();
  float ts = redA[0] + redA[1] + redA[2] + redA[3];
  float ts2 = redB[0] + redB[1] + redB[2] + redB[3];
  float mean = ts * (1.0f / 256.0f);
  float var = ts2 * (1.0f / 256.0f) - mean * mean;
  float rstd = rsqrtf(var + 1e-5f);
  mbuf[t] = (sv - mean) * rstd * ln_m_w[t] + ln_m_b[t];
  __syncthreads();

  if (t < 128) {
    float hv = b1[t];
    for (int d = 0; d < 256; ++d) hv += mbuf[d] * w1[d * 128 + t];
    hid[t] = fmaxf(hv, 0.0f);
  }
  __syncthreads();
  float o = b2[t];
  for (int j = 0; j < 128; ++j) o += hid[j] * w2[j * 256 + t];
  float res = sv + o;
  slots[(long)row * 256 + t] = res;
  if (write_out) out_final[(long)row * 256 + t] = res;
}

// ---------- launch ----------
extern "C" void kernel_launch(void* const* d_in, const int* in_sizes, int n_in,
                              void* d_out, int out_size, void* d_ws, size_t ws_size,
                              hipStream_t stream) {
  (void)in_sizes; (void)n_in; (void)out_size;
  const float* inputs        = (const float*)d_in[0];
  const float* slots_mu      = (const float*)d_in[1];
  const float* slots_logsig  = (const float*)d_in[2];
  const float* ln_in_w       = (const float*)d_in[3];
  const float* ln_in_b       = (const float*)d_in[4];
  const float* ln_s_w        = (const float*)d_in[5];
  const float* ln_s_b        = (const float*)d_in[6];
  const float* Wq            = (const float*)d_in[7];
  const float* Wk            = (const float*)d_in[8];
  const float* Wv            = (const float*)d_in[9];
  const float* Wc            = (const float*)d_in[10];
  const float* w_ih          = (const float*)d_in[11];
  const float* w_hh          = (const float*)d_in[12];
  const float* b_ih          = (const float*)d_in[13];
  const float* b_hh          = (const float*)d_in[14];
  const float* ln_m_w        = (const float*)d_in[15];
  const float* ln_m_b        = (const float*)d_in[16];
  const float* w1            = (const float*)d_in[17];
  const float* b1            = (const float*)d_in[18];
  const float* w2            = (const float*)d_in[19];
  const float* b2            = (const float*)d_in[20];

  const size_t KV_BYTES = 2ull * 32 * 4096 * 256 * sizeof(u16);  // 128 MiB
  bool fast = ws_size >= KV_BYTES + (1u << 20);

  char* ws = (char*)d_ws;
  if (fast) {
    u16* kbuf    = (u16*)ws;                              // 64 MB
    u16* vbuf    = (u16*)(ws + KV_BYTES / 2);             // 64 MB
    char* base   = ws + KV_BYTES;
    float* slots = (float*)base;                          // 256 KB
    float* qbuf  = (float*)(base + 262144);               // 256 KB
    float* U     = (float*)(base + 524288);               // 256 KB
    float* S     = (float*)(base + 786432);               // 4 KB
    // Wt aliases qbuf: consumed by k_proj_mfma before k_qproj first writes qbuf
    u16* Wt      = (u16*)(base + 262144);                 // 256 KB (bf16 [512][256])

    k_slots_init<<<256, 256, 0, stream>>>(slots_mu, slots_logsig, slots);
    k_wt<<<dim3(256, 2), 256, 0, stream>>>(Wk, Wv, Wt);
    k_proj_mfma<<<dim3(2048, 2), 256, 0, stream>>>(inputs, ln_in_w, ln_in_b, Wt, kbuf, vbuf);

    for (int it = 0; it < 3; ++it) {
      hipMemsetAsync(U, 0, (65536 + 1024) * sizeof(float), stream);
      k_qproj<<<256, 256, 0, stream>>>(slots, ln_s_w, ln_s_b, Wq, qbuf);
      k_attn<<<dim3(32, 32), 256, 0, stream>>>(qbuf, kbuf, vbuf, U, S);
      k_slot_update<<<256, 256, 0, stream>>>(U, S, slots, Wc, w_ih, w_hh, b_ih, b_hh,
                                             ln_m_w, ln_m_b, w1, b1, w2, b2,
                                             (float*)d_out, it == 2 ? 1 : 0);
    }
  } else {
    float* slots = (float*)ws;                 // 256 KB
    float* qbuf  = (float*)(ws + 262144);      // 256 KB
    float* U     = (float*)(ws + 524288);      // 256 KB
    float* S     = (float*)(ws + 786432);      // 4 KB

    k_slots_init<<<256, 256, 0, stream>>>(slots_mu, slots_logsig, slots);
    for (int it = 0; it < 3; ++it) {
      hipMemsetAsync(U, 0, (65536 + 1024) * sizeof(float), stream);
      k_qproj<<<256, 256, 0, stream>>>(slots, ln_s_w, ln_s_b, Wq, qbuf);
      k_fused_attn<<<dim3(128, 32), 256, 0, stream>>>(inputs, ln_in_w, ln_in_b,
                                                      Wk, Wv, qbuf, U, S);
      k_slot_update<<<256, 256, 0, stream>>>(U, S, slots, Wc, w_ih, w_hh, b_ih, b_hh,
                                             ln_m_w, ln_m_b, w1, b1, w2, b2,
                                             (float*)d_out, it == 2 ? 1 : 0);
    }
  }
}

// Round 2
// 808.693 us; speedup vs baseline: 2.0621x; 1.0791x over previous
//
#include <hip/hip_runtime.h>
#include <hip/hip_bf16.h>
#include <stdint.h>

// Problem constants
constexpr int B_ = 32, N_ = 4096, D_ = 256, NH_ = 4, DH_ = 64, NS_ = 8;
constexpr float EPS_ = 1e-8f;

typedef unsigned short u16;
typedef __attribute__((ext_vector_type(8))) short bf16x8;   // 8 bf16 (4 VGPRs)
typedef __attribute__((ext_vector_type(4))) float f32x4;    // MFMA accumulator

__device__ inline u16 f2bf(float f) {
  unsigned u = __float_as_uint(f);
  unsigned r = u + 0x7FFFu + ((u >> 16) & 1u);   // RNE
  return (u16)(r >> 16);
}
__device__ inline float bf2f(u16 u) {
  return __uint_as_float(((unsigned)u) << 16);
}

// Giles single-precision erfinv — same coefficients XLA uses for f32 erf_inv
__device__ inline float erfinv_f(float x) {
  float w = -logf((1.0f - x) * (1.0f + x));
  float p;
  if (w < 5.0f) {
    w = w - 2.5f;
    p = 2.81022636e-08f;
    p = 3.43273939e-07f + p * w;
    p = -3.5233877e-06f + p * w;
    p = -4.39150654e-06f + p * w;
    p = 0.00021858087f + p * w;
    p = -0.00125372503f + p * w;
    p = -0.00417768164f + p * w;
    p = 0.246640727f + p * w;
    p = 1.50140941f + p * w;
  } else {
    w = sqrtf(w) - 3.0f;
    p = -0.000200214257f;
    p = 0.000100950558f + p * w;
    p = 0.00134934322f + p * w;
    p = -0.00367342844f + p * w;
    p = 0.00573950773f + p * w;
    p = -0.0076224613f + p * w;
    p = 0.00943887047f + p * w;
    p = 1.00167406f + p * w;
    p = 2.83297682f + p * w;
  }
  return p * x;
}

// Threefry-2x32, 20 rounds (JAX PRNG), key (0, 42)
__device__ inline void threefry(unsigned k0, unsigned k1, unsigned& x0, unsigned& x1) {
  unsigned ks2 = k0 ^ k1 ^ 0x1BD11BDAu;
  x0 += k0; x1 += k1;
#define TF_R(r) { x0 += x1; x1 = (x1 << (r)) | (x1 >> (32 - (r))); x1 ^= x0; }
  TF_R(13) TF_R(15) TF_R(26) TF_R(6)
  x0 += k1; x1 += ks2 + 1u;
  TF_R(17) TF_R(29) TF_R(16) TF_R(24)
  x0 += ks2; x1 += k0 + 2u;
  TF_R(13) TF_R(15) TF_R(26) TF_R(6)
  x0 += k0; x1 += k1 + 3u;
  TF_R(17) TF_R(29) TF_R(16) TF_R(24)
  x0 += k1; x1 += ks2 + 4u;
  TF_R(13) TF_R(15) TF_R(26) TF_R(6)
  x0 += ks2; x1 += k0 + 5u;
#undef TF_R
}

__device__ inline float bits_to_normal(unsigned bits) {
  float f = __uint_as_float((bits >> 9) | 0x3F800000u) - 1.0f;
  const float lo = -0.99999994f;
  const float span = 2.0f;
  float u = fmaxf(lo, f * span + lo);
  return 1.41421356f * erfinv_f(u);
}

// ---------- kernel 1: slot init — partitionable threefry (jax >= 0.4.36 default) ----------
__global__ __launch_bounds__(256) void k_slots_init(const float* __restrict__ mu,
                                                    const float* __restrict__ logsigma,
                                                    float* __restrict__ slots) {
  unsigned e = blockIdx.x * 256u + threadIdx.x;   // [0, 65536)
  unsigned x0 = 0u, x1 = e;
  threefry(0u, 42u, x0, x1);
  unsigned bits = x0 ^ x1;
  float n = bits_to_normal(bits);
  int d = e & 255;
  slots[e] = mu[d] + expf(logsigma[d]) * n;
}

// ---------- kernel 2: q = LN(slots) @ Wq, pre-scaled by DH^-0.5 ----------
__global__ __launch_bounds__(256) void k_qproj(const float* __restrict__ slots,
                                               const float* __restrict__ ln_w,
                                               const float* __restrict__ ln_b,
                                               const float* __restrict__ Wq,
                                               float* __restrict__ qout) {
  __shared__ float sn[256];
  __shared__ float redA[4], redB[4];
  int row = blockIdx.x, t = threadIdx.x;
  float x = slots[row * 256 + t];
  float s = x, s2 = x * x;
#pragma unroll
  for (int off = 32; off; off >>= 1) { s += __shfl_xor(s, off); s2 += __shfl_xor(s2, off); }
  if ((t & 63) == 0) { redA[t >> 6] = s; redB[t >> 6] = s2; }
  __syncthreads();
  float ts = redA[0] + redA[1] + redA[2] + redA[3];
  float ts2 = redB[0] + redB[1] + redB[2] + redB[3];
  float m = ts * (1.0f / 256.0f);
  float var = ts2 * (1.0f / 256.0f) - m * m;
  float rstd = rsqrtf(var + 1e-5f);
  sn[t] = (x - m) * rstd * ln_w[t] + ln_b[t];
  __syncthreads();
  float a = 0.0f;
  for (int k = 0; k < 256; ++k) a += sn[k] * Wq[k * 256 + t];
  qout[row * 256 + t] = a * 0.125f;
}

// ---------- kernel W: transpose Wk/Wv -> bf16 Wt[512][256] (B^T layout for MFMA) ----------
__global__ __launch_bounds__(256) void k_wt(const float* __restrict__ Wk,
                                            const float* __restrict__ Wv,
                                            u16* __restrict__ Wt) {
  int n = blockIdx.x;                      // 0..255 (column of W)
  int t = threadIdx.x;                     // k
  const float* src = blockIdx.y ? Wv : Wk;
  Wt[((blockIdx.y * 256 + n) << 8) + t] = f2bf(src[t * 256 + n]);
}

// ---------- kernel G: transpose GRU weight [768][256] -> [256][768] fp32 ----------
__global__ __launch_bounds__(256) void k_gru_t(const float* __restrict__ src,
                                               float* __restrict__ dst) {
  __shared__ float tile[32][33];
  int c0 = blockIdx.x * 32;          // k dim (256): 8 blocks
  int r0 = blockIdx.y * 32;          // o dim (768): 24 blocks
  int tx = threadIdx.x & 31, ty = threadIdx.x >> 5;   // 32 x 8
#pragma unroll
  for (int i = 0; i < 32; i += 8)
    tile[ty + i][tx] = src[(long)(r0 + ty + i) * 256 + c0 + tx];
  __syncthreads();
#pragma unroll
  for (int i = 0; i < 32; i += 8)
    dst[(long)(c0 + ty + i) * 768 + r0 + tx] = tile[tx][ty + i];
}

// ---------- kernel 3a: LN(inputs) + K/V projection via MFMA (v2: 8 waves) ----------
// Grid (2048, 2): x = 64-row tile, y: 0 -> Wk -> kbuf, 1 -> Wv -> vbuf.
// Block = 512 threads (8 waves). Wave tile 64 rows x 32 cols (acc 4x2 = 32 VGPRs).
// LDS: bf16 A tile [64][264] = 33792 B; epilogue overlays per-wave [32][40] u16
// regions (row stride 80 B = 5 x 16 B, odd -> conflict-free b128 reads).
__global__ __launch_bounds__(512, 4) void k_proj_mfma2(
    const float* __restrict__ in,
    const float* __restrict__ ln_w, const float* __restrict__ ln_b,
    const u16* __restrict__ Wt,
    u16* __restrict__ kbuf, u16* __restrict__ vbuf) {
  constexpr int LDA = 264;                       // 256 + 8 bf16 pad
  __shared__ __align__(16) u16 Asm[64 * LDA];    // 33792 B
  int t = threadIdx.x;
  int w = t >> 6, lane = t & 63;
  int q = lane >> 4, r = lane & 15;
  long row0 = (long)blockIdx.x * 64;
  int half = blockIdx.y;                         // 0=K, 1=V

  // ---- Phase 1: LN of 64 rows -> bf16 LDS A-tile (8 rows per wave) ----
  float4 lw = ((const float4*)ln_w)[lane];
  float4 lb = ((const float4*)ln_b)[lane];
#pragma unroll 4
  for (int j = 0; j < 8; ++j) {
    int rr = w * 8 + j;
    float4 v = ((const float4*)(in + (row0 + rr) * D_))[lane];
    float s = v.x + v.y + v.z + v.w;
    float s2 = v.x * v.x + v.y * v.y + v.z * v.z + v.w * v.w;
#pragma unroll
    for (int off = 32; off; off >>= 1) { s += __shfl_xor(s, off); s2 += __shfl_xor(s2, off); }
    float m = s * (1.0f / 256.0f);
    float var = s2 * (1.0f / 256.0f) - m * m;
    float rstd = rsqrtf(var + 1e-5f);
    unsigned p0 = (unsigned)f2bf((v.x - m) * rstd * lw.x + lb.x)
                | ((unsigned)f2bf((v.y - m) * rstd * lw.y + lb.y) << 16);
    unsigned p1 = (unsigned)f2bf((v.z - m) * rstd * lw.z + lb.z)
                | ((unsigned)f2bf((v.w - m) * rstd * lw.w + lb.w) << 16);
    *(uint2*)&Asm[rr * LDA + lane * 4] = make_uint2(p0, p1);
  }
  __syncthreads();

  // ---- Phase 2: K-loop; wave computes 64x32 via 4x2 16x16 frags ----
  f32x4 acc[4][2];
#pragma unroll
  for (int mf = 0; mf < 4; ++mf)
#pragma unroll
    for (int nf = 0; nf < 2; ++nf) acc[mf][nf] = (f32x4)0.0f;

  const u16* wt_base = Wt + (long)(half * 256 + w * 32) * 256;
#pragma unroll 2
  for (int k0 = 0; k0 < 256; k0 += 32) {
    bf16x8 a[4], b[2];
#pragma unroll
    for (int mf = 0; mf < 4; ++mf)
      a[mf] = *(const bf16x8*)&Asm[(mf * 16 + r) * LDA + k0 + q * 8];
#pragma unroll
    for (int nf = 0; nf < 2; ++nf)
      b[nf] = *(const bf16x8*)&wt_base[(nf * 16 + r) * 256 + k0 + q * 8];
#pragma unroll
    for (int mf = 0; mf < 4; ++mf)
#pragma unroll
      for (int nf = 0; nf < 2; ++nf)
        acc[mf][nf] = __builtin_amdgcn_mfma_f32_16x16x32_bf16(a[mf], b[nf], acc[mf][nf], 0, 0, 0);
  }

  // ---- Epilogue: per-wave private restage, 2 passes of 32 rows ----
  __syncthreads();                               // all waves done reading A-tile
  u16* st = Asm + w * 1280;                      // [32][40] u16, 2560 B per wave
  u16* outp = half ? vbuf : kbuf;
#pragma unroll
  for (int p = 0; p < 2; ++p) {
#pragma unroll
    for (int m2 = 0; m2 < 2; ++m2)
#pragma unroll
      for (int nf = 0; nf < 2; ++nf)
#pragma unroll
        for (int rr = 0; rr < 4; ++rr)
          st[(m2 * 16 + q * 4 + rr) * 40 + nf * 16 + r] = f2bf(acc[p * 2 + m2][nf][rr]);
    // same-wave LDS RAW: compiler inserts lgkmcnt; DS pipe is in-order per wave
#pragma unroll
    for (int s = 0; s < 2; ++s) {
      int rw = s * 16 + (lane >> 2);
      int cc = (lane & 3) * 8;
      uint4 val = *(const uint4*)&st[rw * 40 + cc];
      *(uint4*)&outp[(row0 + p * 32 + rw) * 256 + w * 32 + cc] = val;
    }
  }
}

// ---------- kernel 3b: streaming attention, atomic reduction (mid tier) ----------
__global__ __launch_bounds__(256) void k_attn(
    const float* __restrict__ qbuf,
    const u16* __restrict__ kbuf, const u16* __restrict__ vbuf,
    float* __restrict__ U, float* __restrict__ S) {
  __shared__ float redS[2048];
  __shared__ float sredS[32];
  int b = blockIdx.y, chunk = blockIdx.x;
  int t = threadIdx.x;
  int wave = t >> 6, lane = t & 63;

  for (int e = t; e < 2048; e += 256) redS[e] = 0.0f;
  if (t < 32) sredS[t] = 0.0f;

  float qv[8][4];
#pragma unroll
  for (int i = 0; i < 8; ++i) {
    float4 qq = *(const float4*)(qbuf + ((long)(b * 8 + i)) * 256 + lane * 4);
    qv[i][0] = qq.x; qv[i][1] = qq.y; qv[i][2] = qq.z; qv[i][3] = qq.w;
  }
  float acc[8][4];
  float sacc[8];
#pragma unroll
  for (int i = 0; i < 8; ++i) {
    sacc[i] = 0.0f;
    acc[i][0] = acc[i][1] = acc[i][2] = acc[i][3] = 0.0f;
  }
  __syncthreads();

  long jbase = (long)b * N_ + chunk * 128;
  for (int jj = wave; jj < 128; jj += 4) {
    long off = (jbase + jj) * 256 + lane * 4;
    ushort4 k4 = *(const ushort4*)(kbuf + off);
    ushort4 v4 = *(const ushort4*)(vbuf + off);
    float k0 = bf2f(k4.x), k1 = bf2f(k4.y), k2 = bf2f(k4.z), k3 = bf2f(k4.w);

    float d[8];
#pragma unroll
    for (int i = 0; i < 8; ++i)
      d[i] = qv[i][0] * k0 + qv[i][1] * k1 + qv[i][2] * k2 + qv[i][3] * k3;
#pragma unroll
    for (int off2 = 1; off2 < 16; off2 <<= 1) {
#pragma unroll
      for (int i = 0; i < 8; ++i) d[i] += __shfl_xor(d[i], off2);
    }
    float mx = d[0];
#pragma unroll
    for (int i = 1; i < 8; ++i) mx = fmaxf(mx, d[i]);
    float e[8], sum = 0.0f;
#pragma unroll
    for (int i = 0; i < 8; ++i) { e[i] = expf(d[i] - mx); sum += e[i]; }
    float inv = 1.0f / sum;

    float v0 = bf2f(v4.x), v1 = bf2f(v4.y), v2 = bf2f(v4.z), v3 = bf2f(v4.w);
#pragma unroll
    for (int i = 0; i < 8; ++i) {
      float a = e[i] * inv + EPS_;
      sacc[i] += a;
      acc[i][0] += a * v0; acc[i][1] += a * v1; acc[i][2] += a * v2; acc[i][3] += a * v3;
    }
  }

#pragma unroll
  for (int i = 0; i < 8; ++i) {
    atomicAdd(&redS[i * 256 + lane * 4 + 0], acc[i][0]);
    atomicAdd(&redS[i * 256 + lane * 4 + 1], acc[i][1]);
    atomicAdd(&redS[i * 256 + lane * 4 + 2], acc[i][2]);
    atomicAdd(&redS[i * 256 + lane * 4 + 3], acc[i][3]);
  }
  if ((lane & 15) == 0) {
    int h = lane >> 4;
#pragma unroll
    for (int i = 0; i < 8; ++i) atomicAdd(&sredS[i * 4 + h], sacc[i]);
  }
  __syncthreads();

  for (int e = t; e < 2048; e += 256)
    atomicAdd(&U[((long)b * 8 + (e >> 8)) * 256 + (e & 255)], redS[e]);
  if (t < 32) atomicAdd(&S[b * 32 + t], sredS[t]);
}

// ---------- kernel 3b-v2: streaming attention, partial stores (no atomics) ----------
// P[chunk][b][slot][256], Sp[chunk][b][32]
__global__ __launch_bounds__(256) void k_attn2(
    const float* __restrict__ qbuf,
    const u16* __restrict__ kbuf, const u16* __restrict__ vbuf,
    float* __restrict__ P, float* __restrict__ Sp) {
  __shared__ float redS[2048];
  __shared__ float sredS[32];
  int b = blockIdx.y, chunk = blockIdx.x;
  int t = threadIdx.x;
  int wave = t >> 6, lane = t & 63;

  for (int e = t; e < 2048; e += 256) redS[e] = 0.0f;
  if (t < 32) sredS[t] = 0.0f;

  float qv[8][4];
#pragma unroll
  for (int i = 0; i < 8; ++i) {
    float4 qq = *(const float4*)(qbuf + ((long)(b * 8 + i)) * 256 + lane * 4);
    qv[i][0] = qq.x; qv[i][1] = qq.y; qv[i][2] = qq.z; qv[i][3] = qq.w;
  }
  float acc[8][4];
  float sacc[8];
#pragma unroll
  for (int i = 0; i < 8; ++i) {
    sacc[i] = 0.0f;
    acc[i][0] = acc[i][1] = acc[i][2] = acc[i][3] = 0.0f;
  }
  __syncthreads();

  long jbase = (long)b * N_ + chunk * 128;
  for (int jj = wave; jj < 128; jj += 4) {
    long off = (jbase + jj) * 256 + lane * 4;
    ushort4 k4 = *(const ushort4*)(kbuf + off);
    ushort4 v4 = *(const ushort4*)(vbuf + off);
    float k0 = bf2f(k4.x), k1 = bf2f(k4.y), k2 = bf2f(k4.z), k3 = bf2f(k4.w);

    float d[8];
#pragma unroll
    for (int i = 0; i < 8; ++i)
      d[i] = qv[i][0] * k0 + qv[i][1] * k1 + qv[i][2] * k2 + qv[i][3] * k3;
#pragma unroll
    for (int off2 = 1; off2 < 16; off2 <<= 1) {
#pragma unroll
      for (int i = 0; i < 8; ++i) d[i] += __shfl_xor(d[i], off2);
    }
    float mx = d[0];
#pragma unroll
    for (int i = 1; i < 8; ++i) mx = fmaxf(mx, d[i]);
    float e[8], sum = 0.0f;
#pragma unroll
    for (int i = 0; i < 8; ++i) { e[i] = expf(d[i] - mx); sum += e[i]; }
    float inv = 1.0f / sum;

    float v0 = bf2f(v4.x), v1 = bf2f(v4.y), v2 = bf2f(v4.z), v3 = bf2f(v4.w);
#pragma unroll
    for (int i = 0; i < 8; ++i) {
      float a = e[i] * inv + EPS_;
      sacc[i] += a;
      acc[i][0] += a * v0; acc[i][1] += a * v1; acc[i][2] += a * v2; acc[i][3] += a * v3;
    }
  }

#pragma unroll
  for (int i = 0; i < 8; ++i) {
    atomicAdd(&redS[i * 256 + lane * 4 + 0], acc[i][0]);
    atomicAdd(&redS[i * 256 + lane * 4 + 1], acc[i][1]);
    atomicAdd(&redS[i * 256 + lane * 4 + 2], acc[i][2]);
    atomicAdd(&redS[i * 256 + lane * 4 + 3], acc[i][3]);
  }
  if ((lane & 15) == 0) {
    int h = lane >> 4;
#pragma unroll
    for (int i = 0; i < 8; ++i) atomicAdd(&sredS[i * 4 + h], sacc[i]);
  }
  __syncthreads();

  long pbase = ((long)chunk * 32 + b) * 2048;
  for (int e = t; e < 2048; e += 256) P[pbase + e] = redS[e];
  if (t < 32) Sp[((long)chunk * 32 + b) * 32 + t] = sredS[t];
}

// ---------- kernel 4 (mid tier): normalize + Wc + GRU + LN + MLP ----------
__global__ __launch_bounds__(256) void k_slot_update(
    const float* __restrict__ U, const float* __restrict__ S,
    float* __restrict__ slots,
    const float* __restrict__ Wc,
    const float* __restrict__ w_ih, const float* __restrict__ w_hh,
    const float* __restrict__ b_ih, const float* __restrict__ b_hh,
    const float* __restrict__ ln_m_w, const float* __restrict__ ln_m_b,
    const float* __restrict__ w1, const float* __restrict__ b1,
    const float* __restrict__ w2, const float* __restrict__ b2,
    float* __restrict__ out_final, int write_out) {
  __shared__ float un[256], upd[256], hprev[256], mbuf[256], hid[128];
  __shared__ float redA[4], redB[4];
  int row = blockIdx.x, t = threadIdx.x;

  float denom = S[row * 4 + (t >> 6)];
  un[t] = U[(long)row * 256 + t] / denom;
  float hp = slots[(long)row * 256 + t];
  hprev[t] = hp;
  __syncthreads();

  float a = 0.0f;
  for (int k = 0; k < 256; ++k) a += un[k] * Wc[k * 256 + t];
  upd[t] = a;
  __syncthreads();

  float gxr = b_ih[t], gxz = b_ih[256 + t], gxn = b_ih[512 + t];
  float ghr = b_hh[t], ghz = b_hh[256 + t], ghn = b_hh[512 + t];
  const float4* u4 = (const float4*)upd;
  const float4* h4 = (const float4*)hprev;
  const float4* wr = (const float4*)(w_ih + (long)t * 256);
  const float4* wz = (const float4*)(w_ih + (long)(256 + t) * 256);
  const float4* wn = (const float4*)(w_ih + (long)(512 + t) * 256);
  const float4* vr = (const float4*)(w_hh + (long)t * 256);
  const float4* vz = (const float4*)(w_hh + (long)(256 + t) * 256);
  const float4* vn = (const float4*)(w_hh + (long)(512 + t) * 256);
  for (int k = 0; k < 64; ++k) {
    float4 uu = u4[k], hh = h4[k], w;
    w = wr[k]; gxr += uu.x * w.x + uu.y * w.y + uu.z * w.z + uu.w * w.w;
    w = wz[k]; gxz += uu.x * w.x + uu.y * w.y + uu.z * w.z + uu.w * w.w;
    w = wn[k]; gxn += uu.x * w.x + uu.y * w.y + uu.z * w.z + uu.w * w.w;
    w = vr[k]; ghr += hh.x * w.x + hh.y * w.y + hh.z * w.z + hh.w * w.w;
    w = vz[k]; ghz += hh.x * w.x + hh.y * w.y + hh.z * w.z + hh.w * w.w;
    w = vn[k]; ghn += hh.x * w.x + hh.y * w.y + hh.z * w.z + hh.w * w.w;
  }
  float r = 1.0f / (1.0f + expf(-(gxr + ghr)));
  float z = 1.0f / (1.0f + expf(-(gxz + ghz)));
  float ng = tanhf(gxn + r * ghn);
  float sv = (1.0f - z) * ng + z * hp;

  float s1 = sv, s2v = sv * sv;
#pragma unroll
  for (int off = 32; off; off >>= 1) { s1 += __shfl_xor(s1, off); s2v += __shfl_xor(s2v, off); }
  if ((t & 63) == 0) { redA[t >> 6] = s1; redB[t >> 6] = s2v; }
  __syncthreads();
  float ts = redA[0] + redA[1] + redA[2] + redA[3];
  float ts2 = redB[0] + redB[1] + redB[2] + redB[3];
  float mean = ts * (1.0f / 256.0f);
  float var = ts2 * (1.0f / 256.0f) - mean * mean;
  float rstd = rsqrtf(var + 1e-5f);
  mbuf[t] = (sv - mean) * rstd * ln_m_w[t] + ln_m_b[t];
  __syncthreads();

  if (t < 128) {
    float hv = b1[t];
    for (int d = 0; d < 256; ++d) hv += mbuf[d] * w1[d * 128 + t];
    hid[t] = fmaxf(hv, 0.0f);
  }
  __syncthreads();
  float o = b2[t];
  for (int j = 0; j < 128; ++j) o += hid[j] * w2[j * 256 + t];
  float res = sv + o;
  slots[(long)row * 256 + t] = res;
  if (write_out) out_final[(long)row * 256 + t] = res;
}

// ---------- kernel 4-v2: partial-sum + coalesced transposed GRU weights ----------
__global__ __launch_bounds__(256) void k_slot_update_t(
    const float* __restrict__ P, const float* __restrict__ Sp,
    float* __restrict__ slots,
    const float* __restrict__ Wc,
    const float* __restrict__ wTih, const float* __restrict__ wThh,
    const float* __restrict__ b_ih, const float* __restrict__ b_hh,
    const float* __restrict__ ln_m_w, const float* __restrict__ ln_m_b,
    const float* __restrict__ w1, const float* __restrict__ b1,
    const float* __restrict__ w2, const float* __restrict__ b2,
    float* __restrict__ out_final, int write_out) {
  __shared__ float un[256], upd[256], hprev[256], mbuf[256], hid[128];
  __shared__ float redA[4], redB[4];
  int row = blockIdx.x, t = threadIdx.x;
  int b = row >> 3, sl = row & 7;

  // Reduce the 32 chunk-partials (deterministic order, coalesced)
  float au = 0.0f;
#pragma unroll 4
  for (int c = 0; c < 32; ++c)
    au += P[(((long)c * 32 + b) * 8 + sl) * 256 + t];
  float dn = 0.0f;
  int h = t >> 6;
#pragma unroll 4
  for (int c = 0; c < 32; ++c)
    dn += Sp[((long)c * 32 + b) * 32 + sl * 4 + h];
  un[t] = au / dn;
  float hp = slots[(long)row * 256 + t];
  hprev[t] = hp;
  __syncthreads();

  float a = 0.0f;
  for (int k = 0; k < 256; ++k) a += un[k] * Wc[k * 256 + t];
  upd[t] = a;
  __syncthreads();

  // GRU matvecs with transposed weights: wT[k][768], loads coalesced over t
  float gxr = b_ih[t], gxz = b_ih[256 + t], gxn = b_ih[512 + t];
  float ghr = b_hh[t], ghz = b_hh[256 + t], ghn = b_hh[512 + t];
#pragma unroll 4
  for (int k = 0; k < 256; ++k) {
    float uk = upd[k], hk = hprev[k];
    const float* wi = wTih + (long)k * 768;
    const float* wh = wThh + (long)k * 768;
    gxr += uk * wi[t];
    gxz += uk * wi[256 + t];
    gxn += uk * wi[512 + t];
    ghr += hk * wh[t];
    ghz += hk * wh[256 + t];
    ghn += hk * wh[512 + t];
  }
  float r = 1.0f / (1.0f + expf(-(gxr + ghr)));
  float z = 1.0f / (1.0f + expf(-(gxz + ghz)));
  float ng = tanhf(gxn + r * ghn);
  float sv = (1.0f - z) * ng + z * hp;

  float s1 = sv, s2v = sv * sv;
#pragma unroll
  for (int off = 32; off; off >>= 1) { s1 += __shfl_xor(s1, off); s2v += __shfl_xor(s2v, off); }
  if ((t & 63) == 0) { redA[t >> 6] = s1; redB[t >> 6] = s2v; }
  __syncthreads();
  float ts = redA[0] + redA[1] + redA[2] + redA[3];
  float ts2 = redB[0] + redB[1] + redB[2] + redB[3];
  float mean = ts * (1.0f / 256.0f);
  float var = ts2 * (1.0f / 256.0f) - mean * mean;
  float rstd = rsqrtf(var + 1e-5f);
  mbuf[t] = (sv - mean) * rstd * ln_m_w[t] + ln_m_b[t];
  __syncthreads();

  if (t < 128) {
    float hv = b1[t];
    for (int d = 0; d < 256; ++d) hv += mbuf[d] * w1[d * 128 + t];
    hid[t] = fmaxf(hv, 0.0f);
  }
  __syncthreads();
  float o = b2[t];
  for (int j = 0; j < 128; ++j) o += hid[j] * w2[j * 256 + t];
  float res = sv + o;
  slots[(long)row * 256 + t] = res;
  if (write_out) out_final[(long)row * 256 + t] = res;
}

// ---------- kernel 3-fallback: fused LN+proj+attention (96 KB LDS) ----------
__global__ __launch_bounds__(256) void k_fused_attn(
    const float* __restrict__ in,
    const float* __restrict__ ln_w, const float* __restrict__ ln_b,
    const float* __restrict__ Wk, const float* __restrict__ Wv,
    const float* __restrict__ qbuf,
    float* __restrict__ U, float* __restrict__ S) {
  __shared__ __align__(16) float ldsf[24576];
  float* xs = ldsf;
  float* kf = ldsf + 8192;
  float* vf = ldsf + 16384;
  float* qs    = ldsf;
  float* redS  = ldsf + 2048;
  float* sredS = ldsf + 4096;

  int b = blockIdx.y, chunk = blockIdx.x;
  int t = threadIdx.x;
  int wave = t >> 6, lane = t & 63;
  long row0 = (long)b * N_ + (long)chunk * 32;

  for (int j = 0; j < 8; ++j) {
    int r = wave * 8 + j;
    const float4* rp = (const float4*)(in + (row0 + r) * D_);
    float4 v = rp[lane];
    float s = v.x + v.y + v.z + v.w;
    float s2 = v.x * v.x + v.y * v.y + v.z * v.z + v.w * v.w;
#pragma unroll
    for (int off = 32; off; off >>= 1) { s += __shfl_xor(s, off); s2 += __shfl_xor(s2, off); }
    float m = s * (1.0f / 256.0f);
    float var = s2 * (1.0f / 256.0f) - m * m;
    float rstd = rsqrtf(var + 1e-5f);
    int c = lane * 4;
    xs[r * 256 + c + 0] = (v.x - m) * rstd * ln_w[c + 0] + ln_b[c + 0];
    xs[r * 256 + c + 1] = (v.y - m) * rstd * ln_w[c + 1] + ln_b[c + 1];
    xs[r * 256 + c + 2] = (v.z - m) * rstd * ln_w[c + 2] + ln_b[c + 2];
    xs[r * 256 + c + 3] = (v.w - m) * rstd * ln_w[c + 3] + ln_b[c + 3];
  }
  __syncthreads();

  {
    int tx = t & 31, ty = t >> 5;
    const float* W = (tx < 16) ? Wk : Wv;
    float* obf = (tx < 16) ? kf : vf;
    int col0 = (tx & 15) * 16;
    float acc2[4][16];
#pragma unroll
    for (int r = 0; r < 4; ++r)
#pragma unroll
      for (int c = 0; c < 16; ++c) acc2[r][c] = 0.0f;

    for (int k = 0; k < 256; ++k) {
      const float4* wp = (const float4*)(W + k * 256 + col0);
      float4 w0 = wp[0], w1 = wp[1], w2 = wp[2], w3 = wp[3];
#pragma unroll
      for (int r = 0; r < 4; ++r) {
        float x = xs[(ty * 4 + r) * 256 + k];
        acc2[r][0]  += x * w0.x; acc2[r][1]  += x * w0.y; acc2[r][2]  += x * w0.z; acc2[r][3]  += x * w0.w;
        acc2[r][4]  += x * w1.x; acc2[r][5]  += x * w1.y; acc2[r][6]  += x * w1.z; acc2[r][7]  += x * w1.w;
        acc2[r][8]  += x * w2.x; acc2[r][9]  += x * w2.y; acc2[r][10] += x * w2.z; acc2[r][11] += x * w2.w;
        acc2[r][12] += x * w3.x; acc2[r][13] += x * w3.y; acc2[r][14] += x * w3.z; acc2[r][15] += x * w3.w;
      }
    }
#pragma unroll
    for (int r = 0; r < 4; ++r) {
      float4* dst = (float4*)&obf[(ty * 4 + r) * 256 + col0];
      dst[0] = make_float4(acc2[r][0],  acc2[r][1],  acc2[r][2],  acc2[r][3]);
      dst[1] = make_float4(acc2[r][4],  acc2[r][5],  acc2[r][6],  acc2[r][7]);
      dst[2] = make_float4(acc2[r][8],  acc2[r][9],  acc2[r][10], acc2[r][11]);
      dst[3] = make_float4(acc2[r][12], acc2[r][13], acc2[r][14], acc2[r][15]);
    }
  }
  __syncthreads();

#pragma unroll
  for (int i = 0; i < 8; ++i) qs[i * 256 + t] = qbuf[((long)b * 8 + i) * 256 + t];
  for (int e = t; e < 2048; e += 256) redS[e] = 0.0f;
  if (t < 32) sredS[t] = 0.0f;
  __syncthreads();

  float qv[8][4];
#pragma unroll
  for (int i = 0; i < 8; ++i) {
    float4 qq = *(const float4*)&qs[i * 256 + lane * 4];
    qv[i][0] = qq.x; qv[i][1] = qq.y; qv[i][2] = qq.z; qv[i][3] = qq.w;
  }
  float acc[8][4];
  float sacc[8];
#pragma unroll
  for (int i = 0; i < 8; ++i) {
    sacc[i] = 0.0f;
    acc[i][0] = acc[i][1] = acc[i][2] = acc[i][3] = 0.0f;
  }

  for (int jj = wave; jj < 32; jj += 4) {
    float4 k4 = *(const float4*)&kf[jj * 256 + lane * 4];
    float d[8];
#pragma unroll
    for (int i = 0; i < 8; ++i)
      d[i] = qv[i][0] * k4.x + qv[i][1] * k4.y + qv[i][2] * k4.z + qv[i][3] * k4.w;
#pragma unroll
    for (int off2 = 1; off2 < 16; off2 <<= 1) {
#pragma unroll
      for (int i = 0; i < 8; ++i) d[i] += __shfl_xor(d[i], off2);
    }
    float mx = d[0];
#pragma unroll
    for (int i = 1; i < 8; ++i) mx = fmaxf(mx, d[i]);
    float e[8], sum = 0.0f;
#pragma unroll
    for (int i = 0; i < 8; ++i) { e[i] = expf(d[i] - mx); sum += e[i]; }
    float inv = 1.0f / sum;

    float4 v4 = *(const float4*)&vf[jj * 256 + lane * 4];
#pragma unroll
    for (int i = 0; i < 8; ++i) {
      float a = e[i] * inv + EPS_;
      sacc[i] += a;
      acc[i][0] += a * v4.x; acc[i][1] += a * v4.y; acc[i][2] += a * v4.z; acc[i][3] += a * v4.w;
    }
  }

#pragma unroll
  for (int i = 0; i < 8; ++i) {
    atomicAdd(&redS[i * 256 + lane * 4 + 0], acc[i][0]);
    atomicAdd(&redS[i * 256 + lane * 4 + 1], acc[i][1]);
    atomicAdd(&redS[i * 256 + lane * 4 + 2], acc[i][2]);
    atomicAdd(&redS[i * 256 + lane * 4 + 3], acc[i][3]);
  }
  if ((lane & 15) == 0) {
    int h = lane >> 4;
#pragma unroll
    for (int i = 0; i < 8; ++i) atomicAdd(&sredS[i * 4 + h], sacc[i]);
  }
  __syncthreads();

  for (int e = t; e < 2048; e += 256)
    atomicAdd(&U[((long)b * 8 + (e >> 8)) * 256 + (e & 255)], redS[e]);
  if (t < 32) atomicAdd(&S[b * 32 + t], sredS[t]);
}

// ---------- launch ----------
extern "C" void kernel_launch(void* const* d_in, const int* in_sizes, int n_in,
                              void* d_out, int out_size, void* d_ws, size_t ws_size,
                              hipStream_t stream) {
  (void)in_sizes; (void)n_in; (void)out_size;
  const float* inputs        = (const float*)d_in[0];
  const float* slots_mu      = (const float*)d_in[1];
  const float* slots_logsig  = (const float*)d_in[2];
  const float* ln_in_w       = (const float*)d_in[3];
  const float* ln_in_b       = (const float*)d_in[4];
  const float* ln_s_w        = (const float*)d_in[5];
  const float* ln_s_b        = (const float*)d_in[6];
  const float* Wq            = (const float*)d_in[7];
  const float* Wk            = (const float*)d_in[8];
  const float* Wv            = (const float*)d_in[9];
  const float* Wc            = (const float*)d_in[10];
  const float* w_ih          = (const float*)d_in[11];
  const float* w_hh          = (const float*)d_in[12];
  const float* b_ih          = (const float*)d_in[13];
  const float* b_hh          = (const float*)d_in[14];
  const float* ln_m_w        = (const float*)d_in[15];
  const float* ln_m_b        = (const float*)d_in[16];
  const float* w1            = (const float*)d_in[17];
  const float* b1            = (const float*)d_in[18];
  const float* w2            = (const float*)d_in[19];
  const float* b2            = (const float*)d_in[20];

  const size_t KV_BYTES = 2ull * 32 * 4096 * 256 * sizeof(u16);  // 128 MiB
  char* ws = (char*)d_ws;

  if (ws_size >= KV_BYTES + (12ull << 20)) {
    // ---- full fast path: MFMA proj + partial-store attn + transposed GRU ----
    u16* kbuf    = (u16*)ws;                              // 64 MB
    u16* vbuf    = (u16*)(ws + KV_BYTES / 2);             // 64 MB
    char* base   = ws + KV_BYTES;
    float* slots = (float*)base;                          // 256 KB
    float* qbuf  = (float*)(base + (256ull << 10));       // 256 KB
    u16*   Wt    = (u16*)(base + (256ull << 10));         // aliases qbuf (dead before k_qproj)
    float* P     = (float*)(base + (512ull << 10));       // 8 MB
    float* Sp    = (float*)(base + (512ull << 10) + (8ull << 20));          // 128 KB
    float* wTih  = (float*)(base + (512ull << 10) + (8ull << 20) + (128ull << 10));  // 768 KB
    float* wThh  = (float*)(base + (512ull << 10) + (8ull << 20) + (128ull << 10) + (768ull << 10)); // 768 KB

    k_slots_init<<<256, 256, 0, stream>>>(slots_mu, slots_logsig, slots);
    k_gru_t<<<dim3(8, 24), 256, 0, stream>>>(w_ih, wTih);
    k_gru_t<<<dim3(8, 24), 256, 0, stream>>>(w_hh, wThh);
    k_wt<<<dim3(256, 2), 256, 0, stream>>>(Wk, Wv, Wt);
    k_proj_mfma2<<<dim3(2048, 2), 512, 0, stream>>>(inputs, ln_in_w, ln_in_b, Wt, kbuf, vbuf);

    for (int it = 0; it < 3; ++it) {
      k_qproj<<<256, 256, 0, stream>>>(slots, ln_s_w, ln_s_b, Wq, qbuf);
      k_attn2<<<dim3(32, 32), 256, 0, stream>>>(qbuf, kbuf, vbuf, P, Sp);
      k_slot_update_t<<<256, 256, 0, stream>>>(P, Sp, slots, Wc, wTih, wThh, b_ih, b_hh,
                                               ln_m_w, ln_m_b, w1, b1, w2, b2,
                                               (float*)d_out, it == 2 ? 1 : 0);
    }
  } else if (ws_size >= KV_BYTES + (1ull << 20)) {
    // ---- mid tier (round-1 structure, new proj kernel) ----
    u16* kbuf    = (u16*)ws;
    u16* vbuf    = (u16*)(ws + KV_BYTES / 2);
    char* base   = ws + KV_BYTES;
    float* slots = (float*)base;                          // 256 KB
    float* qbuf  = (float*)(base + 262144);               // 256 KB
    float* U     = (float*)(base + 524288);               // 256 KB
    float* S     = (float*)(base + 786432);               // 4 KB
    u16* Wt      = (u16*)(base + 262144);                 // aliases qbuf

    k_slots_init<<<256, 256, 0, stream>>>(slots_mu, slots_logsig, slots);
    k_wt<<<dim3(256, 2), 256, 0, stream>>>(Wk, Wv, Wt);
    k_proj_mfma2<<<dim3(2048, 2), 512, 0, stream>>>(inputs, ln_in_w, ln_in_b, Wt, kbuf, vbuf);

    for (int it = 0; it < 3; ++it) {
      hipMemsetAsync(U, 0, (65536 + 1024) * sizeof(float), stream);
      k_qproj<<<256, 256, 0, stream>>>(slots, ln_s_w, ln_s_b, Wq, qbuf);
      k_attn<<<dim3(32, 32), 256, 0, stream>>>(qbuf, kbuf, vbuf, U, S);
      k_slot_update<<<256, 256, 0, stream>>>(U, S, slots, Wc, w_ih, w_hh, b_ih, b_hh,
                                             ln_m_w, ln_m_b, w1, b1, w2, b2,
                                             (float*)d_out, it == 2 ? 1 : 0);
    }
  } else {
    // ---- fallback: fused LN+proj+attention each iteration ----
    float* slots = (float*)ws;                 // 256 KB
    float* qbuf  = (float*)(ws + 262144);      // 256 KB
    float* U     = (float*)(ws + 524288);      // 256 KB
    float* S     = (float*)(ws + 786432);      // 4 KB

    k_slots_init<<<256, 256, 0, stream>>>(slots_mu, slots_logsig, slots);
    for (int it = 0; it < 3; ++it) {
      hipMemsetAsync(U, 0, (65536 + 1024) * sizeof(float), stream);
      k_qproj<<<256, 256, 0, stream>>>(slots, ln_s_w, ln_s_b, Wq, qbuf);
      k_fused_attn<<<dim3(128, 32), 256, 0, stream>>>(inputs, ln_in_w, ln_in_b,
                                                      Wk, Wv, qbuf, U, S);
      k_slot_update<<<256, 256, 0, stream>>>(U, S, slots, Wc, w_ih, w_hh, b_ih, b_hh,
                                             ln_m_w, ln_m_b, w1, b1, w2, b2,
                                             (float*)d_out, it == 2 ? 1 : 0);
    }
  }
}

// Round 3
// 656.354 us; speedup vs baseline: 2.5407x; 1.2321x over previous
//
#include <hip/hip_runtime.h>
#include <hip/hip_bf16.h>
#include <stdint.h>

// Problem constants
constexpr int B_ = 32, N_ = 4096, D_ = 256, NH_ = 4, DH_ = 64, NS_ = 8;
constexpr float EPS_ = 1e-8f;

typedef unsigned short u16;
typedef __attribute__((ext_vector_type(8))) short bf16x8;   // 8 bf16 (4 VGPRs)
typedef __attribute__((ext_vector_type(4))) float f32x4;    // MFMA accumulator

__device__ inline u16 f2bf(float f) {
  unsigned u = __float_as_uint(f);
  unsigned r = u + 0x7FFFu + ((u >> 16) & 1u);   // RNE
  return (u16)(r >> 16);
}
__device__ inline float bf2f(u16 u) {
  return __uint_as_float(((unsigned)u) << 16);
}

// Giles single-precision erfinv — same coefficients XLA uses for f32 erf_inv
__device__ inline float erfinv_f(float x) {
  float w = -logf((1.0f - x) * (1.0f + x));
  float p;
  if (w < 5.0f) {
    w = w - 2.5f;
    p = 2.81022636e-08f;
    p = 3.43273939e-07f + p * w;
    p = -3.5233877e-06f + p * w;
    p = -4.39150654e-06f + p * w;
    p = 0.00021858087f + p * w;
    p = -0.00125372503f + p * w;
    p = -0.00417768164f + p * w;
    p = 0.246640727f + p * w;
    p = 1.50140941f + p * w;
  } else {
    w = sqrtf(w) - 3.0f;
    p = -0.000200214257f;
    p = 0.000100950558f + p * w;
    p = 0.00134934322f + p * w;
    p = -0.00367342844f + p * w;
    p = 0.00573950773f + p * w;
    p = -0.0076224613f + p * w;
    p = 0.00943887047f + p * w;
    p = 1.00167406f + p * w;
    p = 2.83297682f + p * w;
  }
  return p * x;
}

// Threefry-2x32, 20 rounds (JAX PRNG), key (0, 42)
__device__ inline void threefry(unsigned k0, unsigned k1, unsigned& x0, unsigned& x1) {
  unsigned ks2 = k0 ^ k1 ^ 0x1BD11BDAu;
  x0 += k0; x1 += k1;
#define TF_R(r) { x0 += x1; x1 = (x1 << (r)) | (x1 >> (32 - (r))); x1 ^= x0; }
  TF_R(13) TF_R(15) TF_R(26) TF_R(6)
  x0 += k1; x1 += ks2 + 1u;
  TF_R(17) TF_R(29) TF_R(16) TF_R(24)
  x0 += ks2; x1 += k0 + 2u;
  TF_R(13) TF_R(15) TF_R(26) TF_R(6)
  x0 += k0; x1 += k1 + 3u;
  TF_R(17) TF_R(29) TF_R(16) TF_R(24)
  x0 += k1; x1 += ks2 + 4u;
  TF_R(13) TF_R(15) TF_R(26) TF_R(6)
  x0 += ks2; x1 += k0 + 5u;
#undef TF_R
}

__device__ inline float bits_to_normal(unsigned bits) {
  float f = __uint_as_float((bits >> 9) | 0x3F800000u) - 1.0f;
  const float lo = -0.99999994f;
  const float span = 2.0f;
  float u = fmaxf(lo, f * span + lo);
  return 1.41421356f * erfinv_f(u);
}

// ---------- kernel 1: slot init ----------
__global__ __launch_bounds__(256) void k_slots_init(const float* __restrict__ mu,
                                                    const float* __restrict__ logsigma,
                                                    float* __restrict__ slots) {
  unsigned e = blockIdx.x * 256u + threadIdx.x;   // [0, 65536)
  unsigned x0 = 0u, x1 = e;
  threefry(0u, 42u, x0, x1);
  unsigned bits = x0 ^ x1;
  float n = bits_to_normal(bits);
  int d = e & 255;
  slots[e] = mu[d] + expf(logsigma[d]) * n;
}

// ---------- kernel 2 (mid/fallback): q = LN(slots) @ Wq ----------
__global__ __launch_bounds__(256) void k_qproj(const float* __restrict__ slots,
                                               const float* __restrict__ ln_w,
                                               const float* __restrict__ ln_b,
                                               const float* __restrict__ Wq,
                                               float* __restrict__ qout) {
  __shared__ float sn[256];
  __shared__ float redA[4], redB[4];
  int row = blockIdx.x, t = threadIdx.x;
  float x = slots[row * 256 + t];
  float s = x, s2 = x * x;
#pragma unroll
  for (int off = 32; off; off >>= 1) { s += __shfl_xor(s, off); s2 += __shfl_xor(s2, off); }
  if ((t & 63) == 0) { redA[t >> 6] = s; redB[t >> 6] = s2; }
  __syncthreads();
  float ts = redA[0] + redA[1] + redA[2] + redA[3];
  float ts2 = redB[0] + redB[1] + redB[2] + redB[3];
  float m = ts * (1.0f / 256.0f);
  float var = ts2 * (1.0f / 256.0f) - m * m;
  float rstd = rsqrtf(var + 1e-5f);
  sn[t] = (x - m) * rstd * ln_w[t] + ln_b[t];
  __syncthreads();
  float a = 0.0f;
  for (int k = 0; k < 256; ++k) a += sn[k] * Wq[k * 256 + t];
  qout[row * 256 + t] = a * 0.125f;
}

// ---------- kernel 2-v2 (fast): qproj split over 4 k-chunks, 1024 blocks ----------
__global__ __launch_bounds__(256) void k_qproj2(const float* __restrict__ slots,
                                                const float* __restrict__ ln_w,
                                                const float* __restrict__ ln_b,
                                                const float* __restrict__ Wq,
                                                float* __restrict__ qout) {
  __shared__ float sn[256];
  __shared__ float part[4][64];
  __shared__ float redA[4], redB[4];
  int row = blockIdx.x, g = blockIdx.y, t = threadIdx.x;
  float x = slots[row * 256 + t];
  float s = x, s2 = x * x;
#pragma unroll
  for (int off = 32; off; off >>= 1) { s += __shfl_xor(s, off); s2 += __shfl_xor(s2, off); }
  if ((t & 63) == 0) { redA[t >> 6] = s; redB[t >> 6] = s2; }
  __syncthreads();
  float ts = redA[0] + redA[1] + redA[2] + redA[3];
  float ts2 = redB[0] + redB[1] + redB[2] + redB[3];
  float m = ts * (1.0f / 256.0f);
  float var = ts2 * (1.0f / 256.0f) - m * m;
  float rstd = rsqrtf(var + 1e-5f);
  sn[t] = (x - m) * rstd * ln_w[t] + ln_b[t];
  __syncthreads();
  int c = t & 63, kq = t >> 6;
  int col = g * 64 + c;
  float a = 0.0f;
#pragma unroll 8
  for (int k = kq * 64; k < kq * 64 + 64; ++k) a += sn[k] * Wq[k * 256 + col];
  part[kq][c] = a;
  __syncthreads();
  if (t < 64)
    qout[row * 256 + g * 64 + t] =
        (part[0][t] + part[1][t] + part[2][t] + part[3][t]) * 0.125f;
}

// ---------- kernel W (mid): transpose Wk/Wv -> bf16 Wt[512][256] ----------
__global__ __launch_bounds__(256) void k_wt(const float* __restrict__ Wk,
                                            const float* __restrict__ Wv,
                                            u16* __restrict__ Wt) {
  int n = blockIdx.x;
  int t = threadIdx.x;
  const float* src = blockIdx.y ? Wv : Wk;
  Wt[((blockIdx.y * 256 + n) << 8) + t] = f2bf(src[t * 256 + n]);
}

// ---------- kernel W2 (fast): Wk/Wv -> MFMA-fragment-ordered bf16 Wt2 ----------
// Wt2[(((m*16+cb)*8 + ks)*64 + lane)*8 + j] = W_m[ks*32 + (lane>>4)*8 + j][cb*16 + (lane&15)]
__global__ __launch_bounds__(64) void k_wt2(const float* __restrict__ Wk,
                                            const float* __restrict__ Wv,
                                            u16* __restrict__ Wt2) {
  int cb = blockIdx.x, m = blockIdx.y, ks = blockIdx.z;
  int lane = threadIdx.x;
  const float* W = m ? Wv : Wk;
  int col = cb * 16 + (lane & 15);
  int kbase = ks * 32 + (lane >> 4) * 8;
  unsigned pk[4];
#pragma unroll
  for (int j = 0; j < 4; ++j) {
    u16 lo = f2bf(W[(long)(kbase + 2 * j) * 256 + col]);
    u16 hi = f2bf(W[(long)(kbase + 2 * j + 1) * 256 + col]);
    pk[j] = (unsigned)lo | ((unsigned)hi << 16);
  }
  *(uint4*)&Wt2[(long)(((m * 16 + cb) * 8 + ks) * 64 + lane) * 8] =
      make_uint4(pk[0], pk[1], pk[2], pk[3]);
}

// ---------- kernel G: transpose GRU weight [768][256] -> [256][768] fp32 ----------
__global__ __launch_bounds__(256) void k_gru_t(const float* __restrict__ src,
                                               float* __restrict__ dst) {
  __shared__ float tile[32][33];
  int c0 = blockIdx.x * 32;
  int r0 = blockIdx.y * 32;
  int tx = threadIdx.x & 31, ty = threadIdx.x >> 5;
#pragma unroll
  for (int i = 0; i < 32; i += 8)
    tile[ty + i][tx] = src[(long)(r0 + ty + i) * 256 + c0 + tx];
  __syncthreads();
#pragma unroll
  for (int i = 0; i < 32; i += 8)
    dst[(long)(c0 + ty + i) * 768 + r0 + tx] = tile[tx][ty + i];
}

// ---------- kernel 3a (fast): LN + K AND V projection in one pass via MFMA ----------
// Grid 2048; block 512 thr (8 waves). Wave w: matrix m=w>>2 (0=K,1=V), cols (w&3)*64..+63.
// Input read ONCE, LN ONCE. B loads coalesced from fragment-ordered Wt2.
__global__ __launch_bounds__(512, 4) void k_proj_mfma3(
    const float* __restrict__ in,
    const float* __restrict__ ln_w, const float* __restrict__ ln_b,
    const u16* __restrict__ Wt2,
    u16* __restrict__ kbuf, u16* __restrict__ vbuf) {
  constexpr int LDA = 264;                        // u16, 528 B rows (16B aligned)
  __shared__ __align__(16) u16 lds[18432];        // 36864 B: A-tile (16896 u16) / epilogue (8x2304)
  u16* Asm = lds;
  int t = threadIdx.x;
  int w = t >> 6, lane = t & 63;
  int q = lane >> 4, r = lane & 15;
  long row0 = (long)blockIdx.x * 64;
  int m = w >> 2;

  // ---- Phase 1: LN of 64 rows -> bf16 LDS A-tile (8 rows/wave, loads pre-issued) ----
  float4 lw = ((const float4*)ln_w)[lane];
  float4 lb = ((const float4*)ln_b)[lane];
  float4 vr[8];
#pragma unroll
  for (int j = 0; j < 8; ++j)
    vr[j] = ((const float4*)(in + (row0 + w * 8 + j) * D_))[lane];
#pragma unroll
  for (int j = 0; j < 8; ++j) {
    int rr = w * 8 + j;
    float4 v = vr[j];
    float s = v.x + v.y + v.z + v.w;
    float s2 = v.x * v.x + v.y * v.y + v.z * v.z + v.w * v.w;
#pragma unroll
    for (int off = 32; off; off >>= 1) { s += __shfl_xor(s, off); s2 += __shfl_xor(s2, off); }
    float mn = s * (1.0f / 256.0f);
    float var = s2 * (1.0f / 256.0f) - mn * mn;
    float rstd = rsqrtf(var + 1e-5f);
    unsigned p0 = (unsigned)f2bf((v.x - mn) * rstd * lw.x + lb.x)
                | ((unsigned)f2bf((v.y - mn) * rstd * lw.y + lb.y) << 16);
    unsigned p1 = (unsigned)f2bf((v.z - mn) * rstd * lw.z + lb.z)
                | ((unsigned)f2bf((v.w - mn) * rstd * lw.w + lb.w) << 16);
    *(uint2*)&Asm[rr * LDA + lane * 4] = make_uint2(p0, p1);
  }
  __syncthreads();

  // ---- Phase 2: K-loop; wave computes 64x64 via 4x4 16x16x32 frags ----
  f32x4 acc[4][4];
#pragma unroll
  for (int mf = 0; mf < 4; ++mf)
#pragma unroll
    for (int nf = 0; nf < 4; ++nf) acc[mf][nf] = (f32x4)0.0f;

#pragma unroll 2
  for (int ks = 0; ks < 8; ++ks) {
    int k0 = ks * 32;
    bf16x8 a[4], b[4];
#pragma unroll
    for (int mf = 0; mf < 4; ++mf)
      a[mf] = *(const bf16x8*)&Asm[(mf * 16 + r) * LDA + k0 + q * 8];
#pragma unroll
    for (int nf = 0; nf < 4; ++nf)
      b[nf] = *(const bf16x8*)&Wt2[(long)(((m * 16 + (w & 3) * 4 + nf) * 8 + ks) * 64 + lane) * 8];
#pragma unroll
    for (int mf = 0; mf < 4; ++mf)
#pragma unroll
      for (int nf = 0; nf < 4; ++nf)
        acc[mf][nf] = __builtin_amdgcn_mfma_f32_16x16x32_bf16(a[mf], b[nf], acc[mf][nf], 0, 0, 0);
  }

  // ---- Epilogue: per-wave [32][72] staging (XOR-swizzled), 2 passes of 32 rows ----
  __syncthreads();                                // all waves done reading A-tile
  u16* st = lds + w * 2304;                       // 32*72 u16 = 4608 B per wave
  u16* outp = m ? vbuf : kbuf;
  int colbase = (w & 3) * 64;
#pragma unroll
  for (int p = 0; p < 2; ++p) {
#pragma unroll
    for (int mfh = 0; mfh < 2; ++mfh) {
      int mf = p * 2 + mfh;
#pragma unroll
      for (int nf = 0; nf < 4; ++nf)
#pragma unroll
        for (int rr = 0; rr < 4; ++rr) {
          int rowp = mfh * 16 + q * 4 + rr;
          int col = nf * 16 + r;
          int colsw = col ^ ((rowp & 7) << 3);
          st[rowp * 72 + colsw] = f2bf(acc[mf][nf][rr]);
        }
    }
    // same-wave LDS RAW: compiler inserts lgkmcnt
#pragma unroll
    for (int sub = 0; sub < 4; ++sub) {
      int rowp = sub * 8 + (lane >> 3);
      int c8 = (lane & 7) * 8;
      int c8s = c8 ^ ((rowp & 7) << 3);
      uint4 val = *(const uint4*)&st[rowp * 72 + c8s];
      *(uint4*)&outp[(row0 + p * 32 + rowp) * 256 + colbase + c8] = val;
    }
  }
}

// ---------- kernel 3a-mid: round-2 MFMA proj (K/V in separate blocks) ----------
__global__ __launch_bounds__(512, 4) void k_proj_mfma2(
    const float* __restrict__ in,
    const float* __restrict__ ln_w, const float* __restrict__ ln_b,
    const u16* __restrict__ Wt,
    u16* __restrict__ kbuf, u16* __restrict__ vbuf) {
  constexpr int LDA = 264;
  __shared__ __align__(16) u16 Asm[64 * LDA];
  int t = threadIdx.x;
  int w = t >> 6, lane = t & 63;
  int q = lane >> 4, r = lane & 15;
  long row0 = (long)blockIdx.x * 64;
  int half = blockIdx.y;

  float4 lw = ((const float4*)ln_w)[lane];
  float4 lb = ((const float4*)ln_b)[lane];
#pragma unroll 4
  for (int j = 0; j < 8; ++j) {
    int rr = w * 8 + j;
    float4 v = ((const float4*)(in + (row0 + rr) * D_))[lane];
    float s = v.x + v.y + v.z + v.w;
    float s2 = v.x * v.x + v.y * v.y + v.z * v.z + v.w * v.w;
#pragma unroll
    for (int off = 32; off; off >>= 1) { s += __shfl_xor(s, off); s2 += __shfl_xor(s2, off); }
    float m = s * (1.0f / 256.0f);
    float var = s2 * (1.0f / 256.0f) - m * m;
    float rstd = rsqrtf(var + 1e-5f);
    unsigned p0 = (unsigned)f2bf((v.x - m) * rstd * lw.x + lb.x)
                | ((unsigned)f2bf((v.y - m) * rstd * lw.y + lb.y) << 16);
    unsigned p1 = (unsigned)f2bf((v.z - m) * rstd * lw.z + lb.z)
                | ((unsigned)f2bf((v.w - m) * rstd * lw.w + lb.w) << 16);
    *(uint2*)&Asm[rr * LDA + lane * 4] = make_uint2(p0, p1);
  }
  __syncthreads();

  f32x4 acc[4][2];
#pragma unroll
  for (int mf = 0; mf < 4; ++mf)
#pragma unroll
    for (int nf = 0; nf < 2; ++nf) acc[mf][nf] = (f32x4)0.0f;

  const u16* wt_base = Wt + (long)(half * 256 + w * 32) * 256;
#pragma unroll 2
  for (int k0 = 0; k0 < 256; k0 += 32) {
    bf16x8 a[4], b[2];
#pragma unroll
    for (int mf = 0; mf < 4; ++mf)
      a[mf] = *(const bf16x8*)&Asm[(mf * 16 + r) * LDA + k0 + q * 8];
#pragma unroll
    for (int nf = 0; nf < 2; ++nf)
      b[nf] = *(const bf16x8*)&wt_base[(nf * 16 + r) * 256 + k0 + q * 8];
#pragma unroll
    for (int mf = 0; mf < 4; ++mf)
#pragma unroll
      for (int nf = 0; nf < 2; ++nf)
        acc[mf][nf] = __builtin_amdgcn_mfma_f32_16x16x32_bf16(a[mf], b[nf], acc[mf][nf], 0, 0, 0);
  }

  __syncthreads();
  u16* st = Asm + w * 1280;
  u16* outp = half ? vbuf : kbuf;
#pragma unroll
  for (int p = 0; p < 2; ++p) {
#pragma unroll
    for (int m2 = 0; m2 < 2; ++m2)
#pragma unroll
      for (int nf = 0; nf < 2; ++nf)
#pragma unroll
        for (int rr = 0; rr < 4; ++rr)
          st[(m2 * 16 + q * 4 + rr) * 40 + nf * 16 + r] = f2bf(acc[p * 2 + m2][nf][rr]);
#pragma unroll
    for (int s = 0; s < 2; ++s) {
      int rw = s * 16 + (lane >> 2);
      int cc = (lane & 3) * 8;
      uint4 val = *(const uint4*)&st[rw * 40 + cc];
      *(uint4*)&outp[(row0 + p * 32 + rw) * 256 + w * 32 + cc] = val;
    }
  }
}

// ---------- kernel 3b (mid): streaming attention, atomic reduction ----------
__global__ __launch_bounds__(256) void k_attn(
    const float* __restrict__ qbuf,
    const u16* __restrict__ kbuf, const u16* __restrict__ vbuf,
    float* __restrict__ U, float* __restrict__ S) {
  __shared__ float redS[2048];
  __shared__ float sredS[32];
  int b = blockIdx.y, chunk = blockIdx.x;
  int t = threadIdx.x;
  int wave = t >> 6, lane = t & 63;

  for (int e = t; e < 2048; e += 256) redS[e] = 0.0f;
  if (t < 32) sredS[t] = 0.0f;

  float qv[8][4];
#pragma unroll
  for (int i = 0; i < 8; ++i) {
    float4 qq = *(const float4*)(qbuf + ((long)(b * 8 + i)) * 256 + lane * 4);
    qv[i][0] = qq.x; qv[i][1] = qq.y; qv[i][2] = qq.z; qv[i][3] = qq.w;
  }
  float acc[8][4];
  float sacc[8];
#pragma unroll
  for (int i = 0; i < 8; ++i) {
    sacc[i] = 0.0f;
    acc[i][0] = acc[i][1] = acc[i][2] = acc[i][3] = 0.0f;
  }
  __syncthreads();

  long jbase = (long)b * N_ + chunk * 128;
  for (int jj = wave; jj < 128; jj += 4) {
    long off = (jbase + jj) * 256 + lane * 4;
    ushort4 k4 = *(const ushort4*)(kbuf + off);
    ushort4 v4 = *(const ushort4*)(vbuf + off);
    float k0 = bf2f(k4.x), k1 = bf2f(k4.y), k2 = bf2f(k4.z), k3 = bf2f(k4.w);

    float d[8];
#pragma unroll
    for (int i = 0; i < 8; ++i)
      d[i] = qv[i][0] * k0 + qv[i][1] * k1 + qv[i][2] * k2 + qv[i][3] * k3;
#pragma unroll
    for (int off2 = 1; off2 < 16; off2 <<= 1) {
#pragma unroll
      for (int i = 0; i < 8; ++i) d[i] += __shfl_xor(d[i], off2);
    }
    float mx = d[0];
#pragma unroll
    for (int i = 1; i < 8; ++i) mx = fmaxf(mx, d[i]);
    float e[8], sum = 0.0f;
#pragma unroll
    for (int i = 0; i < 8; ++i) { e[i] = expf(d[i] - mx); sum += e[i]; }
    float inv = 1.0f / sum;

    float v0 = bf2f(v4.x), v1 = bf2f(v4.y), v2 = bf2f(v4.z), v3 = bf2f(v4.w);
#pragma unroll
    for (int i = 0; i < 8; ++i) {
      float a = e[i] * inv + EPS_;
      sacc[i] += a;
      acc[i][0] += a * v0; acc[i][1] += a * v1; acc[i][2] += a * v2; acc[i][3] += a * v3;
    }
  }

#pragma unroll
  for (int i = 0; i < 8; ++i) {
    atomicAdd(&redS[i * 256 + lane * 4 + 0], acc[i][0]);
    atomicAdd(&redS[i * 256 + lane * 4 + 1], acc[i][1]);
    atomicAdd(&redS[i * 256 + lane * 4 + 2], acc[i][2]);
    atomicAdd(&redS[i * 256 + lane * 4 + 3], acc[i][3]);
  }
  if ((lane & 15) == 0) {
    int h = lane >> 4;
#pragma unroll
    for (int i = 0; i < 8; ++i) atomicAdd(&sredS[i * 4 + h], sacc[i]);
  }
  __syncthreads();

  for (int e = t; e < 2048; e += 256)
    atomicAdd(&U[((long)b * 8 + (e >> 8)) * 256 + (e & 255)], redS[e]);
  if (t < 32) atomicAdd(&S[b * 32 + t], sredS[t]);
}

// ---------- kernel 3b-v3 (fast): token-per-lane attention, no shuffles, no atomics ----------
// Grid (32 chunks of 128 tokens, 32 b); block 256 thr; 2 tiles of 64 tokens.
// P[chunk][b][slot][256], Sp[chunk][b][slot*4+head]
__global__ __launch_bounds__(256) void k_attn3(
    const float* __restrict__ qbuf,
    const u16* __restrict__ kbuf, const u16* __restrict__ vbuf,
    float* __restrict__ P, float* __restrict__ Sp) {
  __shared__ __align__(16) u16 Ks[64 * 260];      // 33280 B, stride 520 B (8B aligned, 2-lane banks)
  __shared__ __align__(16) float qs[8 * 256];     // 8192 B
  __shared__ float dw[64 * 33];                   // dots -> weights, padded stride 33
  int b = blockIdx.y, chunk = blockIdx.x;
  int t = threadIdx.x;
  int tok = t & 63;        // QK/SM: token within tile; PV: col-quad
  int sp = t >> 6;         // QK/PV: slot-pair; SM: head

  // stage q (slot-major, pre-scaled by qproj)
  for (int e = t; e < 2048; e += 256) qs[e] = qbuf[(long)b * 2048 + e];

  float acc0[4] = {0.f, 0.f, 0.f, 0.f};   // PV: slot sp*2,   cols tok*4..+3
  float acc1[4] = {0.f, 0.f, 0.f, 0.f};   // PV: slot sp*2+1
  float rden[8] = {0.f, 0.f, 0.f, 0.f, 0.f, 0.f, 0.f, 0.f};  // SM: denom partials

  long tokbase = (long)b * N_ + chunk * 128;
  for (int tile = 0; tile < 2; ++tile) {
    long trow = tokbase + tile * 64;
    __syncthreads();   // protect Ks/dw from previous tile readers (and qs on tile 0)
    // ---- stage K tile: 64 rows x 512 B, fully coalesced 8B units ----
#pragma unroll
    for (int i = 0; i < 16; ++i) {
      int idx = i * 256 + t;            // 0..4095
      int row = idx >> 6, c8 = idx & 63;
      *(uint2*)&Ks[row * 260 + c8 * 4] =
          *(const uint2*)&kbuf[(trow + row) * 256 + c8 * 4];
    }
    __syncthreads();

    // ---- QK: thread (tok, sp): 8 dots = 2 slots x 4 heads, lane-local ----
    float d0[4] = {0.f, 0.f, 0.f, 0.f};
    float d1[4] = {0.f, 0.f, 0.f, 0.f};
#pragma unroll
    for (int h = 0; h < 4; ++h) {
#pragma unroll
      for (int c2 = 0; c2 < 8; ++c2) {
        int cc = h * 8 + c2;
        ushort4 ka = *(const ushort4*)&Ks[tok * 260 + cc * 8];
        ushort4 kb = *(const ushort4*)&Ks[tok * 260 + cc * 8 + 4];
        float k0 = bf2f(ka.x), k1 = bf2f(ka.y), k2 = bf2f(ka.z), k3 = bf2f(ka.w);
        float k4 = bf2f(kb.x), k5 = bf2f(kb.y), k6 = bf2f(kb.z), k7 = bf2f(kb.w);
        float4 qa0 = *(const float4*)&qs[(sp * 2) * 256 + cc * 8];
        float4 qa1 = *(const float4*)&qs[(sp * 2) * 256 + cc * 8 + 4];
        float4 qb0 = *(const float4*)&qs[(sp * 2 + 1) * 256 + cc * 8];
        float4 qb1 = *(const float4*)&qs[(sp * 2 + 1) * 256 + cc * 8 + 4];
        d0[h] += qa0.x * k0 + qa0.y * k1 + qa0.z * k2 + qa0.w * k3
               + qa1.x * k4 + qa1.y * k5 + qa1.z * k6 + qa1.w * k7;
        d1[h] += qb0.x * k0 + qb0.y * k1 + qb0.z * k2 + qb0.w * k3
               + qb1.x * k4 + qb1.y * k5 + qb1.z * k6 + qb1.w * k7;
      }
    }
#pragma unroll
    for (int h = 0; h < 4; ++h) {
      dw[tok * 33 + (sp * 2) * 4 + h] = d0[h];
      dw[tok * 33 + (sp * 2 + 1) * 4 + h] = d1[h];
    }
    __syncthreads();

    // ---- SM: thread (tok, head=sp): softmax over 8 slots, in place, + EPS ----
    {
      float dv[8];
#pragma unroll
      for (int i = 0; i < 8; ++i) dv[i] = dw[tok * 33 + i * 4 + sp];
      float mx = dv[0];
#pragma unroll
      for (int i = 1; i < 8; ++i) mx = fmaxf(mx, dv[i]);
      float sum = 0.f;
#pragma unroll
      for (int i = 0; i < 8; ++i) { dv[i] = expf(dv[i] - mx); sum += dv[i]; }
      float inv = 1.0f / sum;
#pragma unroll
      for (int i = 0; i < 8; ++i) {
        float a = dv[i] * inv + EPS_;
        dw[tok * 33 + i * 4 + sp] = a;
        rden[i] += a;
      }
    }
    __syncthreads();

    // ---- PV: thread (col-quad=tok, sp): stream V from global, accumulate ----
    {
      int col = tok * 4;
      int h = tok >> 4;                  // head of these cols
      int wbase0 = (sp * 2) * 4 + h;
      int wbase1 = (sp * 2 + 1) * 4 + h;
#pragma unroll 4
      for (int j = 0; j < 64; ++j) {
        float w0 = dw[j * 33 + wbase0];
        float w1 = dw[j * 33 + wbase1];
        ushort4 vv = *(const ushort4*)&vbuf[(trow + j) * 256 + col];
        float v0 = bf2f(vv.x), v1 = bf2f(vv.y), v2 = bf2f(vv.z), v3 = bf2f(vv.w);
        acc0[0] += w0 * v0; acc0[1] += w0 * v1; acc0[2] += w0 * v2; acc0[3] += w0 * v3;
        acc1[0] += w1 * v0; acc1[1] += w1 * v1; acc1[2] += w1 * v2; acc1[3] += w1 * v3;
      }
    }
  }

  // ---- write chunk-partials (no atomics) ----
  long pbase = ((long)chunk * 32 + b) * 2048;
  {
    int col = tok * 4;
    *(float4*)&P[pbase + (sp * 2) * 256 + col] = make_float4(acc0[0], acc0[1], acc0[2], acc0[3]);
    *(float4*)&P[pbase + (sp * 2 + 1) * 256 + col] = make_float4(acc1[0], acc1[1], acc1[2], acc1[3]);
  }
  // denom: reduce rden over the 64 token-lanes of each wave (wave = head)
#pragma unroll
  for (int i = 0; i < 8; ++i) {
#pragma unroll
    for (int off = 32; off; off >>= 1) rden[i] += __shfl_xor(rden[i], off);
  }
  if (tok == 0) {
#pragma unroll
    for (int i = 0; i < 8; ++i)
      Sp[((long)chunk * 32 + b) * 32 + i * 4 + sp] = rden[i];
  }
}

// ---------- kernel 4 (mid/fallback): normalize + Wc + GRU + LN + MLP ----------
__global__ __launch_bounds__(256) void k_slot_update(
    const float* __restrict__ U, const float* __restrict__ S,
    float* __restrict__ slots,
    const float* __restrict__ Wc,
    const float* __restrict__ w_ih, const float* __restrict__ w_hh,
    const float* __restrict__ b_ih, const float* __restrict__ b_hh,
    const float* __restrict__ ln_m_w, const float* __restrict__ ln_m_b,
    const float* __restrict__ w1, const float* __restrict__ b1,
    const float* __restrict__ w2, const float* __restrict__ b2,
    float* __restrict__ out_final, int write_out) {
  __shared__ float un[256], upd[256], hprev[256], mbuf[256], hid[128];
  __shared__ float redA[4], redB[4];
  int row = blockIdx.x, t = threadIdx.x;

  float denom = S[row * 4 + (t >> 6)];
  un[t] = U[(long)row * 256 + t] / denom;
  float hp = slots[(long)row * 256 + t];
  hprev[t] = hp;
  __syncthreads();

  float a = 0.0f;
  for (int k = 0; k < 256; ++k) a += un[k] * Wc[k * 256 + t];
  upd[t] = a;
  __syncthreads();

  float gxr = b_ih[t], gxz = b_ih[256 + t], gxn = b_ih[512 + t];
  float ghr = b_hh[t], ghz = b_hh[256 + t], ghn = b_hh[512 + t];
  const float4* u4 = (const float4*)upd;
  const float4* h4 = (const float4*)hprev;
  const float4* wr = (const float4*)(w_ih + (long)t * 256);
  const float4* wz = (const float4*)(w_ih + (long)(256 + t) * 256);
  const float4* wn = (const float4*)(w_ih + (long)(512 + t) * 256);
  const float4* vr = (const float4*)(w_hh + (long)t * 256);
  const float4* vz = (const float4*)(w_hh + (long)(256 + t) * 256);
  const float4* vn = (const float4*)(w_hh + (long)(512 + t) * 256);
  for (int k = 0; k < 64; ++k) {
    float4 uu = u4[k], hh = h4[k], w;
    w = wr[k]; gxr += uu.x * w.x + uu.y * w.y + uu.z * w.z + uu.w * w.w;
    w = wz[k]; gxz += uu.x * w.x + uu.y * w.y + uu.z * w.z + uu.w * w.w;
    w = wn[k]; gxn += uu.x * w.x + uu.y * w.y + uu.z * w.z + uu.w * w.w;
    w = vr[k]; ghr += hh.x * w.x + hh.y * w.y + hh.z * w.z + hh.w * w.w;
    w = vz[k]; ghz += hh.x * w.x + hh.y * w.y + hh.z * w.z + hh.w * w.w;
    w = vn[k]; ghn += hh.x * w.x + hh.y * w.y + hh.z * w.z + hh.w * w.w;
  }
  float r = 1.0f / (1.0f + expf(-(gxr + ghr)));
  float z = 1.0f / (1.0f + expf(-(gxz + ghz)));
  float ng = tanhf(gxn + r * ghn);
  float sv = (1.0f - z) * ng + z * hp;

  float s1 = sv, s2v = sv * sv;
#pragma unroll
  for (int off = 32; off; off >>= 1) { s1 += __shfl_xor(s1, off); s2v += __shfl_xor(s2v, off); }
  if ((t & 63) == 0) { redA[t >> 6] = s1; redB[t >> 6] = s2v; }
  __syncthreads();
  float ts = redA[0] + redA[1] + redA[2] + redA[3];
  float ts2 = redB[0] + redB[1] + redB[2] + redB[3];
  float mean = ts * (1.0f / 256.0f);
  float var = ts2 * (1.0f / 256.0f) - mean * mean;
  float rstd = rsqrtf(var + 1e-5f);
  mbuf[t] = (sv - mean) * rstd * ln_m_w[t] + ln_m_b[t];
  __syncthreads();

  if (t < 128) {
    float hv = b1[t];
    for (int d = 0; d < 256; ++d) hv += mbuf[d] * w1[d * 128 + t];
    hid[t] = fmaxf(hv, 0.0f);
  }
  __syncthreads();
  float o = b2[t];
  for (int j = 0; j < 128; ++j) o += hid[j] * w2[j * 256 + t];
  float res = sv + o;
  slots[(long)row * 256 + t] = res;
  if (write_out) out_final[(long)row * 256 + t] = res;
}

// ---------- kernel 4-v3 (fast): 768 threads, 1 gate output per thread ----------
__global__ __launch_bounds__(768) void k_slot_update3(
    const float* __restrict__ P, const float* __restrict__ Sp,
    float* __restrict__ slots,
    const float* __restrict__ Wc,
    const float* __restrict__ wTih, const float* __restrict__ wThh,
    const float* __restrict__ b_ih, const float* __restrict__ b_hh,
    const float* __restrict__ ln_m_w, const float* __restrict__ ln_m_b,
    const float* __restrict__ w1, const float* __restrict__ b1,
    const float* __restrict__ w2, const float* __restrict__ b2,
    float* __restrict__ out_final, int write_out) {
  __shared__ float un[256], upd[256], hprev[256], mbuf[256], hid[128];
  __shared__ float updS[3][256];
  __shared__ float gxs[768], ghs[768];
  __shared__ float redA[4], redB[4];
  int row = blockIdx.x, t = threadIdx.x;

  if (t < 256) {
    int b = row >> 3, sl = row & 7, h = t >> 6;
    float au = 0.0f, dn = 0.0f;
#pragma unroll 4
    for (int c = 0; c < 32; ++c) {
      au += P[(((long)c * 32 + b) * 8 + sl) * 256 + t];
      dn += Sp[((long)c * 32 + b) * 32 + sl * 4 + h];
    }
    un[t] = au / dn;
    hprev[t] = slots[(long)row * 256 + t];
  }
  __syncthreads();

  // Wc: thread (c = t&255, slice s = t>>8); k-ranges 85/85/86
  {
    int c = t & 255, s = t >> 8;
    int k0 = s * 85, k1 = (s == 2) ? 256 : (k0 + 85);
    float a = 0.0f;
    for (int k = k0; k < k1; ++k) a += un[k] * Wc[k * 256 + c];
    updS[s][c] = a;
  }
  __syncthreads();
  if (t < 256) upd[t] = updS[0][t] + updS[1][t] + updS[2][t];
  __syncthreads();

  // GRU gates: thread t owns gate t (of 768); coalesced transposed weights
  {
    float gx = b_ih[t], gh = b_hh[t];
#pragma unroll 4
    for (int k = 0; k < 256; ++k) {
      float uk = upd[k], hk = hprev[k];
      gx += uk * wTih[(long)k * 768 + t];
      gh += hk * wThh[(long)k * 768 + t];
    }
    gxs[t] = gx; ghs[t] = gh;
  }
  __syncthreads();

  float sv = 0.0f;
  if (t < 256) {
    float r = 1.0f / (1.0f + expf(-(gxs[t] + ghs[t])));
    float z = 1.0f / (1.0f + expf(-(gxs[256 + t] + ghs[256 + t])));
    float ng = tanhf(gxs[512 + t] + r * ghs[512 + t]);
    sv = (1.0f - z) * ng + z * hprev[t];
    float s1 = sv, s2v = sv * sv;
#pragma unroll
    for (int off = 32; off; off >>= 1) { s1 += __shfl_xor(s1, off); s2v += __shfl_xor(s2v, off); }
    if ((t & 63) == 0) { redA[t >> 6] = s1; redB[t >> 6] = s2v; }
  }
  __syncthreads();
  if (t < 256) {
    float ts = redA[0] + redA[1] + redA[2] + redA[3];
    float ts2 = redB[0] + redB[1] + redB[2] + redB[3];
    float mean = ts * (1.0f / 256.0f);
    float var = ts2 * (1.0f / 256.0f) - mean * mean;
    float rstd = rsqrtf(var + 1e-5f);
    mbuf[t] = (sv - mean) * rstd * ln_m_w[t] + ln_m_b[t];
  }
  __syncthreads();
  if (t < 128) {
    float hv = b1[t];
    for (int d = 0; d < 256; ++d) hv += mbuf[d] * w1[d * 128 + t];
    hid[t] = fmaxf(hv, 0.0f);
  }
  __syncthreads();
  if (t < 256) {
    float o = b2[t];
    for (int j = 0; j < 128; ++j) o += hid[j] * w2[j * 256 + t];
    float res = sv + o;
    slots[(long)row * 256 + t] = res;
    if (write_out) out_final[(long)row * 256 + t] = res;
  }
}

// ---------- kernel 3-fallback: fused LN+proj+attention ----------
__global__ __launch_bounds__(256) void k_fused_attn(
    const float* __restrict__ in,
    const float* __restrict__ ln_w, const float* __restrict__ ln_b,
    const float* __restrict__ Wk, const float* __restrict__ Wv,
    const float* __restrict__ qbuf,
    float* __restrict__ U, float* __restrict__ S) {
  __shared__ __align__(16) float ldsf[24576];
  float* xs = ldsf;
  float* kf = ldsf + 8192;
  float* vf = ldsf + 16384;
  float* qs    = ldsf;
  float* redS  = ldsf + 2048;
  float* sredS = ldsf + 4096;

  int b = blockIdx.y, chunk = blockIdx.x;
  int t = threadIdx.x;
  int wave = t >> 6, lane = t & 63;
  long row0 = (long)b * N_ + (long)chunk * 32;

  for (int j = 0; j < 8; ++j) {
    int r = wave * 8 + j;
    const float4* rp = (const float4*)(in + (row0 + r) * D_);
    float4 v = rp[lane];
    float s = v.x + v.y + v.z + v.w;
    float s2 = v.x * v.x + v.y * v.y + v.z * v.z + v.w * v.w;
#pragma unroll
    for (int off = 32; off; off >>= 1) { s += __shfl_xor(s, off); s2 += __shfl_xor(s2, off); }
    float m = s * (1.0f / 256.0f);
    float var = s2 * (1.0f / 256.0f) - m * m;
    float rstd = rsqrtf(var + 1e-5f);
    int c = lane * 4;
    xs[r * 256 + c + 0] = (v.x - m) * rstd * ln_w[c + 0] + ln_b[c + 0];
    xs[r * 256 + c + 1] = (v.y - m) * rstd * ln_w[c + 1] + ln_b[c + 1];
    xs[r * 256 + c + 2] = (v.z - m) * rstd * ln_w[c + 2] + ln_b[c + 2];
    xs[r * 256 + c + 3] = (v.w - m) * rstd * ln_w[c + 3] + ln_b[c + 3];
  }
  __syncthreads();

  {
    int tx = t & 31, ty = t >> 5;
    const float* W = (tx < 16) ? Wk : Wv;
    float* obf = (tx < 16) ? kf : vf;
    int col0 = (tx & 15) * 16;
    float acc2[4][16];
#pragma unroll
    for (int r = 0; r < 4; ++r)
#pragma unroll
      for (int c = 0; c < 16; ++c) acc2[r][c] = 0.0f;

    for (int k = 0; k < 256; ++k) {
      const float4* wp = (const float4*)(W + k * 256 + col0);
      float4 w0 = wp[0], w1 = wp[1], w2 = wp[2], w3 = wp[3];
#pragma unroll
      for (int r = 0; r < 4; ++r) {
        float x = xs[(ty * 4 + r) * 256 + k];
        acc2[r][0]  += x * w0.x; acc2[r][1]  += x * w0.y; acc2[r][2]  += x * w0.z; acc2[r][3]  += x * w0.w;
        acc2[r][4]  += x * w1.x; acc2[r][5]  += x * w1.y; acc2[r][6]  += x * w1.z; acc2[r][7]  += x * w1.w;
        acc2[r][8]  += x * w2.x; acc2[r][9]  += x * w2.y; acc2[r][10] += x * w2.z; acc2[r][11] += x * w2.w;
        acc2[r][12] += x * w3.x; acc2[r][13] += x * w3.y; acc2[r][14] += x * w3.z; acc2[r][15] += x * w3.w;
      }
    }
#pragma unroll
    for (int r = 0; r < 4; ++r) {
      float4* dst = (float4*)&obf[(ty * 4 + r) * 256 + col0];
      dst[0] = make_float4(acc2[r][0],  acc2[r][1],  acc2[r][2],  acc2[r][3]);
      dst[1] = make_float4(acc2[r][4],  acc2[r][5],  acc2[r][6],  acc2[r][7]);
      dst[2] = make_float4(acc2[r][8],  acc2[r][9],  acc2[r][10], acc2[r][11]);
      dst[3] = make_float4(acc2[r][12], acc2[r][13], acc2[r][14], acc2[r][15]);
    }
  }
  __syncthreads();

#pragma unroll
  for (int i = 0; i < 8; ++i) qs[i * 256 + t] = qbuf[((long)b * 8 + i) * 256 + t];
  for (int e = t; e < 2048; e += 256) redS[e] = 0.0f;
  if (t < 32) sredS[t] = 0.0f;
  __syncthreads();

  float qv[8][4];
#pragma unroll
  for (int i = 0; i < 8; ++i) {
    float4 qq = *(const float4*)&qs[i * 256 + lane * 4];
    qv[i][0] = qq.x; qv[i][1] = qq.y; qv[i][2] = qq.z; qv[i][3] = qq.w;
  }
  float acc[8][4];
  float sacc[8];
#pragma unroll
  for (int i = 0; i < 8; ++i) {
    sacc[i] = 0.0f;
    acc[i][0] = acc[i][1] = acc[i][2] = acc[i][3] = 0.0f;
  }

  for (int jj = wave; jj < 32; jj += 4) {
    float4 k4 = *(const float4*)&kf[jj * 256 + lane * 4];
    float d[8];
#pragma unroll
    for (int i = 0; i < 8; ++i)
      d[i] = qv[i][0] * k4.x + qv[i][1] * k4.y + qv[i][2] * k4.z + qv[i][3] * k4.w;
#pragma unroll
    for (int off2 = 1; off2 < 16; off2 <<= 1) {
#pragma unroll
      for (int i = 0; i < 8; ++i) d[i] += __shfl_xor(d[i], off2);
    }
    float mx = d[0];
#pragma unroll
    for (int i = 1; i < 8; ++i) mx = fmaxf(mx, d[i]);
    float e[8], sum = 0.0f;
#pragma unroll
    for (int i = 0; i < 8; ++i) { e[i] = expf(d[i] - mx); sum += e[i]; }
    float inv = 1.0f / sum;

    float4 v4 = *(const float4*)&vf[jj * 256 + lane * 4];
#pragma unroll
    for (int i = 0; i < 8; ++i) {
      float a = e[i] * inv + EPS_;
      sacc[i] += a;
      acc[i][0] += a * v4.x; acc[i][1] += a * v4.y; acc[i][2] += a * v4.z; acc[i][3] += a * v4.w;
    }
  }

#pragma unroll
  for (int i = 0; i < 8; ++i) {
    atomicAdd(&redS[i * 256 + lane * 4 + 0], acc[i][0]);
    atomicAdd(&redS[i * 256 + lane * 4 + 1], acc[i][1]);
    atomicAdd(&redS[i * 256 + lane * 4 + 2], acc[i][2]);
    atomicAdd(&redS[i * 256 + lane * 4 + 3], acc[i][3]);
  }
  if ((lane & 15) == 0) {
    int h = lane >> 4;
#pragma unroll
    for (int i = 0; i < 8; ++i) atomicAdd(&sredS[i * 4 + h], sacc[i]);
  }
  __syncthreads();

  for (int e = t; e < 2048; e += 256)
    atomicAdd(&U[((long)b * 8 + (e >> 8)) * 256 + (e & 255)], redS[e]);
  if (t < 32) atomicAdd(&S[b * 32 + t], sredS[t]);
}

// ---------- launch ----------
extern "C" void kernel_launch(void* const* d_in, const int* in_sizes, int n_in,
                              void* d_out, int out_size, void* d_ws, size_t ws_size,
                              hipStream_t stream) {
  (void)in_sizes; (void)n_in; (void)out_size;
  const float* inputs        = (const float*)d_in[0];
  const float* slots_mu      = (const float*)d_in[1];
  const float* slots_logsig  = (const float*)d_in[2];
  const float* ln_in_w       = (const float*)d_in[3];
  const float* ln_in_b       = (const float*)d_in[4];
  const float* ln_s_w        = (const float*)d_in[5];
  const float* ln_s_b        = (const float*)d_in[6];
  const float* Wq            = (const float*)d_in[7];
  const float* Wk            = (const float*)d_in[8];
  const float* Wv            = (const float*)d_in[9];
  const float* Wc            = (const float*)d_in[10];
  const float* w_ih          = (const float*)d_in[11];
  const float* w_hh          = (const float*)d_in[12];
  const float* b_ih          = (const float*)d_in[13];
  const float* b_hh          = (const float*)d_in[14];
  const float* ln_m_w        = (const float*)d_in[15];
  const float* ln_m_b        = (const float*)d_in[16];
  const float* w1            = (const float*)d_in[17];
  const float* b1            = (const float*)d_in[18];
  const float* w2            = (const float*)d_in[19];
  const float* b2            = (const float*)d_in[20];

  const size_t KV_BYTES = 2ull * 32 * 4096 * 256 * sizeof(u16);  // 128 MiB
  char* ws = (char*)d_ws;

  if (ws_size >= KV_BYTES + (12ull << 20)) {
    // ---- full fast path ----
    u16* kbuf    = (u16*)ws;                              // 64 MB
    u16* vbuf    = (u16*)(ws + KV_BYTES / 2);             // 64 MB
    char* base   = ws + KV_BYTES;
    float* slots = (float*)base;                          // 256 KB
    float* qbuf  = (float*)(base + (256ull << 10));       // 256 KB
    u16*   Wt2   = (u16*)(base + (256ull << 10));         // 256 KB, aliases qbuf (dead before qproj)
    float* P     = (float*)(base + (512ull << 10));       // 8 MB
    float* Sp    = (float*)(base + (512ull << 10) + (8ull << 20));                       // 128 KB
    float* wTih  = (float*)(base + (512ull << 10) + (8ull << 20) + (128ull << 10));      // 768 KB
    float* wThh  = (float*)(base + (512ull << 10) + (8ull << 20) + (128ull << 10) + (768ull << 10)); // 768 KB

    k_slots_init<<<256, 256, 0, stream>>>(slots_mu, slots_logsig, slots);
    k_gru_t<<<dim3(8, 24), 256, 0, stream>>>(w_ih, wTih);
    k_gru_t<<<dim3(8, 24), 256, 0, stream>>>(w_hh, wThh);
    k_wt2<<<dim3(16, 2, 8), 64, 0, stream>>>(Wk, Wv, Wt2);
    k_proj_mfma3<<<2048, 512, 0, stream>>>(inputs, ln_in_w, ln_in_b, Wt2, kbuf, vbuf);

    for (int it = 0; it < 3; ++it) {
      k_qproj2<<<dim3(256, 4), 256, 0, stream>>>(slots, ln_s_w, ln_s_b, Wq, qbuf);
      k_attn3<<<dim3(32, 32), 256, 0, stream>>>(qbuf, kbuf, vbuf, P, Sp);
      k_slot_update3<<<256, 768, 0, stream>>>(P, Sp, slots, Wc, wTih, wThh, b_ih, b_hh,
                                              ln_m_w, ln_m_b, w1, b1, w2, b2,
                                              (float*)d_out, it == 2 ? 1 : 0);
    }
  } else if (ws_size >= KV_BYTES + (1ull << 20)) {
    // ---- mid tier (round-2 structure) ----
    u16* kbuf    = (u16*)ws;
    u16* vbuf    = (u16*)(ws + KV_BYTES / 2);
    char* base   = ws + KV_BYTES;
    float* slots = (float*)base;                          // 256 KB
    float* qbuf  = (float*)(base + 262144);               // 256 KB
    float* U     = (float*)(base + 524288);               // 256 KB
    float* S     = (float*)(base + 786432);               // 4 KB
    u16* Wt      = (u16*)(base + 262144);                 // aliases qbuf

    k_slots_init<<<256, 256, 0, stream>>>(slots_mu, slots_logsig, slots);
    k_wt<<<dim3(256, 2), 256, 0, stream>>>(Wk, Wv, Wt);
    k_proj_mfma2<<<dim3(2048, 2), 512, 0, stream>>>(inputs, ln_in_w, ln_in_b, Wt, kbuf, vbuf);

    for (int it = 0; it < 3; ++it) {
      hipMemsetAsync(U, 0, (65536 + 1024) * sizeof(float), stream);
      k_qproj<<<256, 256, 0, stream>>>(slots, ln_s_w, ln_s_b, Wq, qbuf);
      k_attn<<<dim3(32, 32), 256, 0, stream>>>(qbuf, kbuf, vbuf, U, S);
      k_slot_update<<<256, 256, 0, stream>>>(U, S, slots, Wc, w_ih, w_hh, b_ih, b_hh,
                                             ln_m_w, ln_m_b, w1, b1, w2, b2,
                                             (float*)d_out, it == 2 ? 1 : 0);
    }
  } else {
    // ---- fallback ----
    float* slots = (float*)ws;                 // 256 KB
    float* qbuf  = (float*)(ws + 262144);      // 256 KB
    float* U     = (float*)(ws + 524288);      // 256 KB
    float* S     = (float*)(ws + 786432);      // 4 KB

    k_slots_init<<<256, 256, 0, stream>>>(slots_mu, slots_logsig, slots);
    for (int it = 0; it < 3; ++it) {
      hipMemsetAsync(U, 0, (65536 + 1024) * sizeof(float), stream);
      k_qproj<<<256, 256, 0, stream>>>(slots, ln_s_w, ln_s_b, Wq, qbuf);
      k_fused_attn<<<dim3(128, 32), 256, 0, stream>>>(inputs, ln_in_w, ln_in_b,
                                                      Wk, Wv, qbuf, U, S);
      k_slot_update<<<256, 256, 0, stream>>>(U, S, slots, Wc, w_ih, w_hh, b_ih, b_hh,
                                             ln_m_w, ln_m_b, w1, b1, w2, b2,
                                             (float*)d_out, it == 2 ? 1 : 0);
    }
  }
}

// Round 4
// 564.788 us; speedup vs baseline: 2.9527x; 1.1621x over previous
//
#include <hip/hip_runtime.h>
#include <hip/hip_bf16.h>
#include <stdint.h>

// Problem constants
constexpr int B_ = 32, N_ = 4096, D_ = 256, NH_ = 4, DH_ = 64, NS_ = 8;
constexpr float EPS_ = 1e-8f;

typedef unsigned short u16;
typedef __attribute__((ext_vector_type(8))) short bf16x8;   // 8 bf16 (4 VGPRs)
typedef __attribute__((ext_vector_type(4))) float f32x4;    // MFMA accumulator

__device__ inline u16 f2bf(float f) {
  unsigned u = __float_as_uint(f);
  unsigned r = u + 0x7FFFu + ((u >> 16) & 1u);   // RNE
  return (u16)(r >> 16);
}
__device__ inline float bf2f(u16 u) {
  return __uint_as_float(((unsigned)u) << 16);
}

// Giles single-precision erfinv — same coefficients XLA uses for f32 erf_inv
__device__ inline float erfinv_f(float x) {
  float w = -logf((1.0f - x) * (1.0f + x));
  float p;
  if (w < 5.0f) {
    w = w - 2.5f;
    p = 2.81022636e-08f;
    p = 3.43273939e-07f + p * w;
    p = -3.5233877e-06f + p * w;
    p = -4.39150654e-06f + p * w;
    p = 0.00021858087f + p * w;
    p = -0.00125372503f + p * w;
    p = -0.00417768164f + p * w;
    p = 0.246640727f + p * w;
    p = 1.50140941f + p * w;
  } else {
    w = sqrtf(w) - 3.0f;
    p = -0.000200214257f;
    p = 0.000100950558f + p * w;
    p = 0.00134934322f + p * w;
    p = -0.00367342844f + p * w;
    p = 0.00573950773f + p * w;
    p = -0.0076224613f + p * w;
    p = 0.00943887047f + p * w;
    p = 1.00167406f + p * w;
    p = 2.83297682f + p * w;
  }
  return p * x;
}

// Threefry-2x32, 20 rounds (JAX PRNG), key (0, 42)
__device__ inline void threefry(unsigned k0, unsigned k1, unsigned& x0, unsigned& x1) {
  unsigned ks2 = k0 ^ k1 ^ 0x1BD11BDAu;
  x0 += k0; x1 += k1;
#define TF_R(r) { x0 += x1; x1 = (x1 << (r)) | (x1 >> (32 - (r))); x1 ^= x0; }
  TF_R(13) TF_R(15) TF_R(26) TF_R(6)
  x0 += k1; x1 += ks2 + 1u;
  TF_R(17) TF_R(29) TF_R(16) TF_R(24)
  x0 += ks2; x1 += k0 + 2u;
  TF_R(13) TF_R(15) TF_R(26) TF_R(6)
  x0 += k0; x1 += k1 + 3u;
  TF_R(17) TF_R(29) TF_R(16) TF_R(24)
  x0 += k1; x1 += ks2 + 4u;
  TF_R(13) TF_R(15) TF_R(26) TF_R(6)
  x0 += ks2; x1 += k0 + 5u;
#undef TF_R
}

__device__ inline float bits_to_normal(unsigned bits) {
  float f = __uint_as_float((bits >> 9) | 0x3F800000u) - 1.0f;
  const float lo = -0.99999994f;
  const float span = 2.0f;
  float u = fmaxf(lo, f * span + lo);
  return 1.41421356f * erfinv_f(u);
}

// ---------- kernel 1: slot init ----------
__global__ __launch_bounds__(256) void k_slots_init(const float* __restrict__ mu,
                                                    const float* __restrict__ logsigma,
                                                    float* __restrict__ slots) {
  unsigned e = blockIdx.x * 256u + threadIdx.x;   // [0, 65536)
  unsigned x0 = 0u, x1 = e;
  threefry(0u, 42u, x0, x1);
  unsigned bits = x0 ^ x1;
  float n = bits_to_normal(bits);
  int d = e & 255;
  slots[e] = mu[d] + expf(logsigma[d]) * n;
}

// ---------- kernel 2 (mid/fallback): q = LN(slots) @ Wq ----------
__global__ __launch_bounds__(256) void k_qproj(const float* __restrict__ slots,
                                               const float* __restrict__ ln_w,
                                               const float* __restrict__ ln_b,
                                               const float* __restrict__ Wq,
                                               float* __restrict__ qout) {
  __shared__ float sn[256];
  __shared__ float redA[4], redB[4];
  int row = blockIdx.x, t = threadIdx.x;
  float x = slots[row * 256 + t];
  float s = x, s2 = x * x;
#pragma unroll
  for (int off = 32; off; off >>= 1) { s += __shfl_xor(s, off); s2 += __shfl_xor(s2, off); }
  if ((t & 63) == 0) { redA[t >> 6] = s; redB[t >> 6] = s2; }
  __syncthreads();
  float ts = redA[0] + redA[1] + redA[2] + redA[3];
  float ts2 = redB[0] + redB[1] + redB[2] + redB[3];
  float m = ts * (1.0f / 256.0f);
  float var = ts2 * (1.0f / 256.0f) - m * m;
  float rstd = rsqrtf(var + 1e-5f);
  sn[t] = (x - m) * rstd * ln_w[t] + ln_b[t];
  __syncthreads();
  float a = 0.0f;
  for (int k = 0; k < 256; ++k) a += sn[k] * Wq[k * 256 + t];
  qout[row * 256 + t] = a * 0.125f;
}

// ---------- kernel 2-v2 (fast): qproj split over 4 k-chunks, 1024 blocks ----------
__global__ __launch_bounds__(256) void k_qproj2(const float* __restrict__ slots,
                                                const float* __restrict__ ln_w,
                                                const float* __restrict__ ln_b,
                                                const float* __restrict__ Wq,
                                                float* __restrict__ qout) {
  __shared__ float sn[256];
  __shared__ float part[4][64];
  __shared__ float redA[4], redB[4];
  int row = blockIdx.x, g = blockIdx.y, t = threadIdx.x;
  float x = slots[row * 256 + t];
  float s = x, s2 = x * x;
#pragma unroll
  for (int off = 32; off; off >>= 1) { s += __shfl_xor(s, off); s2 += __shfl_xor(s2, off); }
  if ((t & 63) == 0) { redA[t >> 6] = s; redB[t >> 6] = s2; }
  __syncthreads();
  float ts = redA[0] + redA[1] + redA[2] + redA[3];
  float ts2 = redB[0] + redB[1] + redB[2] + redB[3];
  float m = ts * (1.0f / 256.0f);
  float var = ts2 * (1.0f / 256.0f) - m * m;
  float rstd = rsqrtf(var + 1e-5f);
  sn[t] = (x - m) * rstd * ln_w[t] + ln_b[t];
  __syncthreads();
  int c = t & 63, kq = t >> 6;
  int col = g * 64 + c;
  float a = 0.0f;
#pragma unroll 8
  for (int k = kq * 64; k < kq * 64 + 64; ++k) a += sn[k] * Wq[k * 256 + col];
  part[kq][c] = a;
  __syncthreads();
  if (t < 64)
    qout[row * 256 + g * 64 + t] =
        (part[0][t] + part[1][t] + part[2][t] + part[3][t]) * 0.125f;
}

// ---------- kernel W (mid): transpose Wk/Wv -> bf16 Wt[512][256] ----------
__global__ __launch_bounds__(256) void k_wt(const float* __restrict__ Wk,
                                            const float* __restrict__ Wv,
                                            u16* __restrict__ Wt) {
  int n = blockIdx.x;
  int t = threadIdx.x;
  const float* src = blockIdx.y ? Wv : Wk;
  Wt[((blockIdx.y * 256 + n) << 8) + t] = f2bf(src[t * 256 + n]);
}

// ---------- kernel W2 (fast): Wk/Wv -> MFMA-fragment-ordered bf16 Wt2 ----------
// Wt2[(((m*16+cb)*8 + ks)*64 + lane)*8 + j] = W_m[ks*32 + (lane>>4)*8 + j][cb*16 + (lane&15)]
__global__ __launch_bounds__(64) void k_wt2(const float* __restrict__ Wk,
                                            const float* __restrict__ Wv,
                                            u16* __restrict__ Wt2) {
  int cb = blockIdx.x, m = blockIdx.y, ks = blockIdx.z;
  int lane = threadIdx.x;
  const float* W = m ? Wv : Wk;
  int col = cb * 16 + (lane & 15);
  int kbase = ks * 32 + (lane >> 4) * 8;
  unsigned pk[4];
#pragma unroll
  for (int j = 0; j < 4; ++j) {
    u16 lo = f2bf(W[(long)(kbase + 2 * j) * 256 + col]);
    u16 hi = f2bf(W[(long)(kbase + 2 * j + 1) * 256 + col]);
    pk[j] = (unsigned)lo | ((unsigned)hi << 16);
  }
  *(uint4*)&Wt2[(long)(((m * 16 + cb) * 8 + ks) * 64 + lane) * 8] =
      make_uint4(pk[0], pk[1], pk[2], pk[3]);
}

// ---------- kernel G: transpose GRU weight [768][256] -> [256][768] fp32 ----------
__global__ __launch_bounds__(256) void k_gru_t(const float* __restrict__ src,
                                               float* __restrict__ dst) {
  __shared__ float tile[32][33];
  int c0 = blockIdx.x * 32;
  int r0 = blockIdx.y * 32;
  int tx = threadIdx.x & 31, ty = threadIdx.x >> 5;
#pragma unroll
  for (int i = 0; i < 32; i += 8)
    tile[ty + i][tx] = src[(long)(r0 + ty + i) * 256 + c0 + tx];
  __syncthreads();
#pragma unroll
  for (int i = 0; i < 32; i += 8)
    dst[(long)(c0 + ty + i) * 768 + r0 + tx] = tile[tx][ty + i];
}

// ---------- kernel 3a (fast): LN + K/V projection; K row-major, V TRANSPOSED ----------
// Grid 2048; block 512 (8 waves). Wave w: m=w>>2 (0=K,1=V), cols (w&3)*64..+63.
// A-tile: XOR-swizzled [64][256] bf16 = 32 KB exactly (T2, no pad).
// K waves: staged coalesced epilogue. V waves: direct scatter to Vt[b][dh][tok].
__global__ __launch_bounds__(512, 4) void k_proj_mfma4(
    const float* __restrict__ in,
    const float* __restrict__ ln_w, const float* __restrict__ ln_b,
    const u16* __restrict__ Wt2,
    u16* __restrict__ kbuf, u16* __restrict__ vt) {
  __shared__ __align__(16) u16 lds[16384];        // 32 KB
  int t = threadIdx.x;
  int w = t >> 6, lane = t & 63;
  int q = lane >> 4, r = lane & 15;
  long row0 = (long)blockIdx.x * 64;
  int m = w >> 2;

  // ---- Phase 1: LN of 64 rows -> swizzled bf16 A-tile (8 rows/wave) ----
  float4 lw = ((const float4*)ln_w)[lane];
  float4 lb = ((const float4*)ln_b)[lane];
  float4 vr[8];
#pragma unroll
  for (int j = 0; j < 8; ++j)
    vr[j] = ((const float4*)(in + (row0 + w * 8 + j) * D_))[lane];
#pragma unroll
  for (int j = 0; j < 8; ++j) {
    int rr = w * 8 + j;
    float4 v = vr[j];
    float s = v.x + v.y + v.z + v.w;
    float s2 = v.x * v.x + v.y * v.y + v.z * v.z + v.w * v.w;
#pragma unroll
    for (int off = 32; off; off >>= 1) { s += __shfl_xor(s, off); s2 += __shfl_xor(s2, off); }
    float mn = s * (1.0f / 256.0f);
    float var = s2 * (1.0f / 256.0f) - mn * mn;
    float rstd = rsqrtf(var + 1e-5f);
    unsigned p0 = (unsigned)f2bf((v.x - mn) * rstd * lw.x + lb.x)
                | ((unsigned)f2bf((v.y - mn) * rstd * lw.y + lb.y) << 16);
    unsigned p1 = (unsigned)f2bf((v.z - mn) * rstd * lw.z + lb.z)
                | ((unsigned)f2bf((v.w - mn) * rstd * lw.w + lb.w) << 16);
    int unit = (lane >> 1) ^ (rr & 7);            // 16-B unit swizzle
    *(uint2*)&lds[rr * 256 + unit * 8 + (lane & 1) * 4] = make_uint2(p0, p1);
  }
  __syncthreads();

  // ---- Phase 2: K-loop; wave computes 64x64 via 4x4 16x16x32 frags ----
  f32x4 acc[4][4];
#pragma unroll
  for (int mf = 0; mf < 4; ++mf)
#pragma unroll
    for (int nf = 0; nf < 4; ++nf) acc[mf][nf] = (f32x4)0.0f;

#pragma unroll 2
  for (int ks = 0; ks < 8; ++ks) {
    bf16x8 a[4], b[4];
#pragma unroll
    for (int mf = 0; mf < 4; ++mf) {
      int unit = ((ks * 4 + q) ^ (r & 7));
      a[mf] = *(const bf16x8*)&lds[(mf * 16 + r) * 256 + unit * 8];
    }
#pragma unroll
    for (int nf = 0; nf < 4; ++nf)
      b[nf] = *(const bf16x8*)&Wt2[(long)(((m * 16 + (w & 3) * 4 + nf) * 8 + ks) * 64 + lane) * 8];
#pragma unroll
    for (int mf = 0; mf < 4; ++mf)
#pragma unroll
      for (int nf = 0; nf < 4; ++nf)
        acc[mf][nf] = __builtin_amdgcn_mfma_f32_16x16x32_bf16(a[mf], b[nf], acc[mf][nf], 0, 0, 0);
  }

  __syncthreads();                                // all waves done reading A-tile
  if (m == 0) {
    // ---- K epilogue: per-wave [32][72] staging (XOR-swizzled), coalesced stores ----
    u16* st = lds + w * 2304;                     // w in 0..3 -> 9216 u16 max
    int colbase = (w & 3) * 64;
#pragma unroll
    for (int p = 0; p < 2; ++p) {
#pragma unroll
      for (int mfh = 0; mfh < 2; ++mfh) {
        int mf = p * 2 + mfh;
#pragma unroll
        for (int nf = 0; nf < 4; ++nf)
#pragma unroll
          for (int rr = 0; rr < 4; ++rr) {
            int rowp = mfh * 16 + q * 4 + rr;
            int col = nf * 16 + r;
            int colsw = col ^ ((rowp & 7) << 3);
            st[rowp * 72 + colsw] = f2bf(acc[mf][nf][rr]);
          }
      }
#pragma unroll
      for (int sub = 0; sub < 4; ++sub) {
        int rowp = sub * 8 + (lane >> 3);
        int c8 = (lane & 7) * 8;
        int c8s = c8 ^ ((rowp & 7) << 3);
        uint4 val = *(const uint4*)&st[rowp * 72 + c8s];
        *(uint4*)&kbuf[(row0 + p * 32 + rowp) * 256 + colbase + c8] = val;
      }
    }
  } else {
    // ---- V epilogue: direct transposed scatter Vt[b][dh][tok], 8-B stores ----
    int bb = (int)(row0 >> 12);
    int tloc = (int)(row0 & 4095);
    int colb = (w & 3) * 64;
#pragma unroll
    for (int mf = 0; mf < 4; ++mf)
#pragma unroll
      for (int nf = 0; nf < 4; ++nf) {
        unsigned p0 = (unsigned)f2bf(acc[mf][nf][0]) | ((unsigned)f2bf(acc[mf][nf][1]) << 16);
        unsigned p1 = (unsigned)f2bf(acc[mf][nf][2]) | ((unsigned)f2bf(acc[mf][nf][3]) << 16);
        long dst = ((long)bb * 256 + colb + nf * 16 + r) * 4096 + tloc + mf * 16 + q * 4;
        *(uint2*)&vt[dst] = make_uint2(p0, p1);
      }
  }
}

// ---------- kernel 3a-mid: round-2 MFMA proj (K/V in separate blocks) ----------
__global__ __launch_bounds__(512, 4) void k_proj_mfma2(
    const float* __restrict__ in,
    const float* __restrict__ ln_w, const float* __restrict__ ln_b,
    const u16* __restrict__ Wt,
    u16* __restrict__ kbuf, u16* __restrict__ vbuf) {
  constexpr int LDA = 264;
  __shared__ __align__(16) u16 Asm[64 * LDA];
  int t = threadIdx.x;
  int w = t >> 6, lane = t & 63;
  int q = lane >> 4, r = lane & 15;
  long row0 = (long)blockIdx.x * 64;
  int half = blockIdx.y;

  float4 lw = ((const float4*)ln_w)[lane];
  float4 lb = ((const float4*)ln_b)[lane];
#pragma unroll 4
  for (int j = 0; j < 8; ++j) {
    int rr = w * 8 + j;
    float4 v = ((const float4*)(in + (row0 + rr) * D_))[lane];
    float s = v.x + v.y + v.z + v.w;
    float s2 = v.x * v.x + v.y * v.y + v.z * v.z + v.w * v.w;
#pragma unroll
    for (int off = 32; off; off >>= 1) { s += __shfl_xor(s, off); s2 += __shfl_xor(s2, off); }
    float m = s * (1.0f / 256.0f);
    float var = s2 * (1.0f / 256.0f) - m * m;
    float rstd = rsqrtf(var + 1e-5f);
    unsigned p0 = (unsigned)f2bf((v.x - m) * rstd * lw.x + lb.x)
                | ((unsigned)f2bf((v.y - m) * rstd * lw.y + lb.y) << 16);
    unsigned p1 = (unsigned)f2bf((v.z - m) * rstd * lw.z + lb.z)
                | ((unsigned)f2bf((v.w - m) * rstd * lw.w + lb.w) << 16);
    *(uint2*)&Asm[rr * LDA + lane * 4] = make_uint2(p0, p1);
  }
  __syncthreads();

  f32x4 acc[4][2];
#pragma unroll
  for (int mf = 0; mf < 4; ++mf)
#pragma unroll
    for (int nf = 0; nf < 2; ++nf) acc[mf][nf] = (f32x4)0.0f;

  const u16* wt_base = Wt + (long)(half * 256 + w * 32) * 256;
#pragma unroll 2
  for (int k0 = 0; k0 < 256; k0 += 32) {
    bf16x8 a[4], b[2];
#pragma unroll
    for (int mf = 0; mf < 4; ++mf)
      a[mf] = *(const bf16x8*)&Asm[(mf * 16 + r) * LDA + k0 + q * 8];
#pragma unroll
    for (int nf = 0; nf < 2; ++nf)
      b[nf] = *(const bf16x8*)&wt_base[(nf * 16 + r) * 256 + k0 + q * 8];
#pragma unroll
    for (int mf = 0; mf < 4; ++mf)
#pragma unroll
      for (int nf = 0; nf < 2; ++nf)
        acc[mf][nf] = __builtin_amdgcn_mfma_f32_16x16x32_bf16(a[mf], b[nf], acc[mf][nf], 0, 0, 0);
  }

  __syncthreads();
  u16* st = Asm + w * 1280;
  u16* outp = half ? vbuf : kbuf;
#pragma unroll
  for (int p = 0; p < 2; ++p) {
#pragma unroll
    for (int m2 = 0; m2 < 2; ++m2)
#pragma unroll
      for (int nf = 0; nf < 2; ++nf)
#pragma unroll
        for (int rr = 0; rr < 4; ++rr)
          st[(m2 * 16 + q * 4 + rr) * 40 + nf * 16 + r] = f2bf(acc[p * 2 + m2][nf][rr]);
#pragma unroll
    for (int s = 0; s < 2; ++s) {
      int rw = s * 16 + (lane >> 2);
      int cc = (lane & 3) * 8;
      uint4 val = *(const uint4*)&st[rw * 40 + cc];
      *(uint4*)&outp[(row0 + p * 32 + rw) * 256 + w * 32 + cc] = val;
    }
  }
}

// ---------- kernel 3b (mid): streaming attention, atomic reduction ----------
__global__ __launch_bounds__(256) void k_attn(
    const float* __restrict__ qbuf,
    const u16* __restrict__ kbuf, const u16* __restrict__ vbuf,
    float* __restrict__ U, float* __restrict__ S) {
  __shared__ float redS[2048];
  __shared__ float sredS[32];
  int b = blockIdx.y, chunk = blockIdx.x;
  int t = threadIdx.x;
  int wave = t >> 6, lane = t & 63;

  for (int e = t; e < 2048; e += 256) redS[e] = 0.0f;
  if (t < 32) sredS[t] = 0.0f;

  float qv[8][4];
#pragma unroll
  for (int i = 0; i < 8; ++i) {
    float4 qq = *(const float4*)(qbuf + ((long)(b * 8 + i)) * 256 + lane * 4);
    qv[i][0] = qq.x; qv[i][1] = qq.y; qv[i][2] = qq.z; qv[i][3] = qq.w;
  }
  float acc[8][4];
  float sacc[8];
#pragma unroll
  for (int i = 0; i < 8; ++i) {
    sacc[i] = 0.0f;
    acc[i][0] = acc[i][1] = acc[i][2] = acc[i][3] = 0.0f;
  }
  __syncthreads();

  long jbase = (long)b * N_ + chunk * 128;
  for (int jj = wave; jj < 128; jj += 4) {
    long off = (jbase + jj) * 256 + lane * 4;
    ushort4 k4 = *(const ushort4*)(kbuf + off);
    ushort4 v4 = *(const ushort4*)(vbuf + off);
    float k0 = bf2f(k4.x), k1 = bf2f(k4.y), k2 = bf2f(k4.z), k3 = bf2f(k4.w);

    float d[8];
#pragma unroll
    for (int i = 0; i < 8; ++i)
      d[i] = qv[i][0] * k0 + qv[i][1] * k1 + qv[i][2] * k2 + qv[i][3] * k3;
#pragma unroll
    for (int off2 = 1; off2 < 16; off2 <<= 1) {
#pragma unroll
      for (int i = 0; i < 8; ++i) d[i] += __shfl_xor(d[i], off2);
    }
    float mx = d[0];
#pragma unroll
    for (int i = 1; i < 8; ++i) mx = fmaxf(mx, d[i]);
    float e[8], sum = 0.0f;
#pragma unroll
    for (int i = 0; i < 8; ++i) { e[i] = expf(d[i] - mx); sum += e[i]; }
    float inv = 1.0f / sum;

    float v0 = bf2f(v4.x), v1 = bf2f(v4.y), v2 = bf2f(v4.z), v3 = bf2f(v4.w);
#pragma unroll
    for (int i = 0; i < 8; ++i) {
      float a = e[i] * inv + EPS_;
      sacc[i] += a;
      acc[i][0] += a * v0; acc[i][1] += a * v1; acc[i][2] += a * v2; acc[i][3] += a * v3;
    }
  }

#pragma unroll
  for (int i = 0; i < 8; ++i) {
    atomicAdd(&redS[i * 256 + lane * 4 + 0], acc[i][0]);
    atomicAdd(&redS[i * 256 + lane * 4 + 1], acc[i][1]);
    atomicAdd(&redS[i * 256 + lane * 4 + 2], acc[i][2]);
    atomicAdd(&redS[i * 256 + lane * 4 + 3], acc[i][3]);
  }
  if ((lane & 15) == 0) {
    int h = lane >> 4;
#pragma unroll
    for (int i = 0; i < 8; ++i) atomicAdd(&sredS[i * 4 + h], sacc[i]);
  }
  __syncthreads();

  for (int e = t; e < 2048; e += 256)
    atomicAdd(&U[((long)b * 8 + (e >> 8)) * 256 + (e & 255)], redS[e]);
  if (t < 32) atomicAdd(&S[b * 32 + t], sredS[t]);
}

// ---------- kernel 3b-v4 (fast): MFMA attention, wave = head, no barriers ----------
// Grid (32 chunks of 128 tokens, 32 b); block 256 thr (4 waves = 4 heads).
// QK^T via mfma (A = q-frag 8 slots + 8 zero rows; B = kbuf rows, native 16B frags);
// softmax-over-slots in C-layout; weights bf16 -> per-wave swizzled LDS tile;
// PV via mfma (A = weight tile; B = Vt rows). P[chunk][b][slot][256], Sp[...].
__global__ __launch_bounds__(256) void k_attn4(
    const float* __restrict__ qbuf,
    const u16* __restrict__ kbuf, const u16* __restrict__ vt,
    float* __restrict__ P, float* __restrict__ Sp) {
  __shared__ __align__(16) u16 abuf[4][16 * 128];   // 4 KB per wave
  int b = blockIdx.y, chunk = blockIdx.x;
  int t = threadIdx.x;
  int h = t >> 6, lane = t & 63;
  int q = lane >> 4, r = lane & 15;
  long tok0 = (long)b * N_ + chunk * 128;

  // q fragments for this head (8 slots, rows 8-15 zero)
  bf16x8 aq[2];
  {
    union { u16 us[8]; bf16x8 v; } pk;
#pragma unroll
    for (int i = 0; i < 8; ++i) pk.us[i] = 0;
    aq[0] = pk.v; aq[1] = pk.v;
    if (r < 8) {
#pragma unroll
      for (int c = 0; c < 2; ++c) {
        const float* qp = qbuf + (long)b * 2048 + r * 256 + h * 64 + c * 32 + q * 8;
        float4 qa = *(const float4*)qp;
        float4 qb = *(const float4*)(qp + 4);
        pk.us[0] = f2bf(qa.x); pk.us[1] = f2bf(qa.y);
        pk.us[2] = f2bf(qa.z); pk.us[3] = f2bf(qa.w);
        pk.us[4] = f2bf(qb.x); pk.us[5] = f2bf(qb.y);
        pk.us[6] = f2bf(qb.z); pk.us[7] = f2bf(qb.w);
        aq[c] = pk.v;
      }
    }
  }

  u16* ab = abuf[h];
  float rden[4] = {0.f, 0.f, 0.f, 0.f};

  // ---- Phase A: QK^T + softmax for 8 groups of 16 tokens ----
#pragma unroll 2
  for (int tg = 0; tg < 8; ++tg) {
    long krow = tok0 + tg * 16 + r;
    bf16x8 bk0 = *(const bf16x8*)&kbuf[krow * 256 + h * 64 + q * 8];
    bf16x8 bk1 = *(const bf16x8*)&kbuf[krow * 256 + h * 64 + 32 + q * 8];
    f32x4 d = (f32x4)0.0f;
    d = __builtin_amdgcn_mfma_f32_16x16x32_bf16(aq[0], bk0, d, 0, 0, 0);
    d = __builtin_amdgcn_mfma_f32_16x16x32_bf16(aq[1], bk1, d, 0, 0, 0);
    // softmax over 8 slots for this token (col = lane&15): regs + shfl_xor(16)
    float mx = fmaxf(fmaxf(d[0], d[1]), fmaxf(d[2], d[3]));
    mx = fmaxf(mx, __shfl_xor(mx, 16));
    float e0 = expf(d[0] - mx), e1 = expf(d[1] - mx);
    float e2 = expf(d[2] - mx), e3 = expf(d[3] - mx);
    float sum = e0 + e1 + e2 + e3;
    sum += __shfl_xor(sum, 16);
    float inv = 1.0f / sum;
    float av[4] = {e0 * inv + EPS_, e1 * inv + EPS_, e2 * inv + EPS_, e3 * inv + EPS_};
    int col = tg * 16 + r;
#pragma unroll
    for (int i = 0; i < 4; ++i) {
      u16 ab16 = 0;
      if (q < 2) {
        ab16 = f2bf(av[i]);
        rden[i] += bf2f(ab16);          // denom from the SAME rounded values
      }
      int rowi = q * 4 + i;             // rows 8-15 get zeros
      int unit = (col >> 3) ^ (rowi & 7);
      ab[rowi * 128 + unit * 8 + (col & 7)] = ab16;
    }
  }

  // reduce denominators across the 16 token-lanes of each quad
#pragma unroll
  for (int i = 0; i < 4; ++i) {
#pragma unroll
    for (int off = 1; off < 16; off <<= 1) rden[i] += __shfl_xor(rden[i], off);
  }

  // ---- Phase B: PV via mfma, K = 128 tokens in 4 steps ----
  f32x4 au[4];
#pragma unroll
  for (int nf = 0; nf < 4; ++nf) au[nf] = (f32x4)0.0f;
#pragma unroll
  for (int ks = 0; ks < 4; ++ks) {
    bf16x8 pa = *(const bf16x8*)&ab[r * 128 + (((ks * 4 + q) ^ (r & 7)) * 8)];
#pragma unroll
    for (int nf = 0; nf < 4; ++nf) {
      bf16x8 bv = *(const bf16x8*)&vt[((long)b * 256 + h * 64 + nf * 16 + r) * 4096
                                      + chunk * 128 + ks * 32 + q * 8];
      au[nf] = __builtin_amdgcn_mfma_f32_16x16x32_bf16(pa, bv, au[nf], 0, 0, 0);
    }
  }

  // ---- write chunk-partials (no atomics) ----
  long pbase = ((long)chunk * 32 + b) * 2048;
  if (q < 2) {
#pragma unroll
    for (int nf = 0; nf < 4; ++nf)
#pragma unroll
      for (int i = 0; i < 4; ++i)
        P[pbase + (q * 4 + i) * 256 + h * 64 + nf * 16 + r] = au[nf][i];
    if (r == 0) {
#pragma unroll
      for (int i = 0; i < 4; ++i)
        Sp[((long)chunk * 32 + b) * 32 + (q * 4 + i) * 4 + h] = rden[i];
    }
  }
}

// ---------- kernel 4 (mid/fallback): normalize + Wc + GRU + LN + MLP ----------
__global__ __launch_bounds__(256) void k_slot_update(
    const float* __restrict__ U, const float* __restrict__ S,
    float* __restrict__ slots,
    const float* __restrict__ Wc,
    const float* __restrict__ w_ih, const float* __restrict__ w_hh,
    const float* __restrict__ b_ih, const float* __restrict__ b_hh,
    const float* __restrict__ ln_m_w, const float* __restrict__ ln_m_b,
    const float* __restrict__ w1, const float* __restrict__ b1,
    const float* __restrict__ w2, const float* __restrict__ b2,
    float* __restrict__ out_final, int write_out) {
  __shared__ float un[256], upd[256], hprev[256], mbuf[256], hid[128];
  __shared__ float redA[4], redB[4];
  int row = blockIdx.x, t = threadIdx.x;

  float denom = S[row * 4 + (t >> 6)];
  un[t] = U[(long)row * 256 + t] / denom;
  float hp = slots[(long)row * 256 + t];
  hprev[t] = hp;
  __syncthreads();

  float a = 0.0f;
  for (int k = 0; k < 256; ++k) a += un[k] * Wc[k * 256 + t];
  upd[t] = a;
  __syncthreads();

  float gxr = b_ih[t], gxz = b_ih[256 + t], gxn = b_ih[512 + t];
  float ghr = b_hh[t], ghz = b_hh[256 + t], ghn = b_hh[512 + t];
  const float4* u4 = (const float4*)upd;
  const float4* h4 = (const float4*)hprev;
  const float4* wr = (const float4*)(w_ih + (long)t * 256);
  const float4* wz = (const float4*)(w_ih + (long)(256 + t) * 256);
  const float4* wn = (const float4*)(w_ih + (long)(512 + t) * 256);
  const float4* vrp = (const float4*)(w_hh + (long)t * 256);
  const float4* vzp = (const float4*)(w_hh + (long)(256 + t) * 256);
  const float4* vnp = (const float4*)(w_hh + (long)(512 + t) * 256);
  for (int k = 0; k < 64; ++k) {
    float4 uu = u4[k], hh = h4[k], w;
    w = wr[k];  gxr += uu.x * w.x + uu.y * w.y + uu.z * w.z + uu.w * w.w;
    w = wz[k];  gxz += uu.x * w.x + uu.y * w.y + uu.z * w.z + uu.w * w.w;
    w = wn[k];  gxn += uu.x * w.x + uu.y * w.y + uu.z * w.z + uu.w * w.w;
    w = vrp[k]; ghr += hh.x * w.x + hh.y * w.y + hh.z * w.z + hh.w * w.w;
    w = vzp[k]; ghz += hh.x * w.x + hh.y * w.y + hh.z * w.z + hh.w * w.w;
    w = vnp[k]; ghn += hh.x * w.x + hh.y * w.y + hh.z * w.z + hh.w * w.w;
  }
  float r = 1.0f / (1.0f + expf(-(gxr + ghr)));
  float z = 1.0f / (1.0f + expf(-(gxz + ghz)));
  float ng = tanhf(gxn + r * ghn);
  float sv = (1.0f - z) * ng + z * hp;

  float s1 = sv, s2v = sv * sv;
#pragma unroll
  for (int off = 32; off; off >>= 1) { s1 += __shfl_xor(s1, off); s2v += __shfl_xor(s2v, off); }
  if ((t & 63) == 0) { redA[t >> 6] = s1; redB[t >> 6] = s2v; }
  __syncthreads();
  float ts = redA[0] + redA[1] + redA[2] + redA[3];
  float ts2 = redB[0] + redB[1] + redB[2] + redB[3];
  float mean = ts * (1.0f / 256.0f);
  float var = ts2 * (1.0f / 256.0f) - mean * mean;
  float rstd = rsqrtf(var + 1e-5f);
  mbuf[t] = (sv - mean) * rstd * ln_m_w[t] + ln_m_b[t];
  __syncthreads();

  if (t < 128) {
    float hv = b1[t];
    for (int d = 0; d < 256; ++d) hv += mbuf[d] * w1[d * 128 + t];
    hid[t] = fmaxf(hv, 0.0f);
  }
  __syncthreads();
  float o = b2[t];
  for (int j = 0; j < 128; ++j) o += hid[j] * w2[j * 256 + t];
  float res = sv + o;
  slots[(long)row * 256 + t] = res;
  if (write_out) out_final[(long)row * 256 + t] = res;
}

// ---------- kernel 4-v3 (fast): 768 threads, 1 gate output per thread ----------
__global__ __launch_bounds__(768) void k_slot_update3(
    const float* __restrict__ P, const float* __restrict__ Sp,
    float* __restrict__ slots,
    const float* __restrict__ Wc,
    const float* __restrict__ wTih, const float* __restrict__ wThh,
    const float* __restrict__ b_ih, const float* __restrict__ b_hh,
    const float* __restrict__ ln_m_w, const float* __restrict__ ln_m_b,
    const float* __restrict__ w1, const float* __restrict__ b1,
    const float* __restrict__ w2, const float* __restrict__ b2,
    float* __restrict__ out_final, int write_out) {
  __shared__ float un[256], upd[256], hprev[256], mbuf[256], hid[128];
  __shared__ float updS[3][256];
  __shared__ float gxs[768], ghs[768];
  __shared__ float redA[4], redB[4];
  int row = blockIdx.x, t = threadIdx.x;

  if (t < 256) {
    int b = row >> 3, sl = row & 7, h = t >> 6;
    float au = 0.0f, dn = 0.0f;
#pragma unroll 4
    for (int c = 0; c < 32; ++c) {
      au += P[(((long)c * 32 + b) * 8 + sl) * 256 + t];
      dn += Sp[((long)c * 32 + b) * 32 + sl * 4 + h];
    }
    un[t] = au / dn;
    hprev[t] = slots[(long)row * 256 + t];
  }
  __syncthreads();

  {
    int c = t & 255, s = t >> 8;
    int k0 = s * 85, k1 = (s == 2) ? 256 : (k0 + 85);
    float a = 0.0f;
    for (int k = k0; k < k1; ++k) a += un[k] * Wc[k * 256 + c];
    updS[s][c] = a;
  }
  __syncthreads();
  if (t < 256) upd[t] = updS[0][t] + updS[1][t] + updS[2][t];
  __syncthreads();

  {
    float gx = b_ih[t], gh = b_hh[t];
#pragma unroll 4
    for (int k = 0; k < 256; ++k) {
      float uk = upd[k], hk = hprev[k];
      gx += uk * wTih[(long)k * 768 + t];
      gh += hk * wThh[(long)k * 768 + t];
    }
    gxs[t] = gx; ghs[t] = gh;
  }
  __syncthreads();

  float sv = 0.0f;
  if (t < 256) {
    float r = 1.0f / (1.0f + expf(-(gxs[t] + ghs[t])));
    float z = 1.0f / (1.0f + expf(-(gxs[256 + t] + ghs[256 + t])));
    float ng = tanhf(gxs[512 + t] + r * ghs[512 + t]);
    sv = (1.0f - z) * ng + z * hprev[t];
    float s1 = sv, s2v = sv * sv;
#pragma unroll
    for (int off = 32; off; off >>= 1) { s1 += __shfl_xor(s1, off); s2v += __shfl_xor(s2v, off); }
    if ((t & 63) == 0) { redA[t >> 6] = s1; redB[t >> 6] = s2v; }
  }
  __syncthreads();
  if (t < 256) {
    float ts = redA[0] + redA[1] + redA[2] + redA[3];
    float ts2 = redB[0] + redB[1] + redB[2] + redB[3];
    float mean = ts * (1.0f / 256.0f);
    float var = ts2 * (1.0f / 256.0f) - mean * mean;
    float rstd = rsqrtf(var + 1e-5f);
    mbuf[t] = (sv - mean) * rstd * ln_m_w[t] + ln_m_b[t];
  }
  __syncthreads();
  if (t < 128) {
    float hv = b1[t];
    for (int d = 0; d < 256; ++d) hv += mbuf[d] * w1[d * 128 + t];
    hid[t] = fmaxf(hv, 0.0f);
  }
  __syncthreads();
  if (t < 256) {
    float o = b2[t];
    for (int j = 0; j < 128; ++j) o += hid[j] * w2[j * 256 + t];
    float res = sv + o;
    slots[(long)row * 256 + t] = res;
    if (write_out) out_final[(long)row * 256 + t] = res;
  }
}

// ---------- kernel 3-fallback: fused LN+proj+attention ----------
__global__ __launch_bounds__(256) void k_fused_attn(
    const float* __restrict__ in,
    const float* __restrict__ ln_w, const float* __restrict__ ln_b,
    const float* __restrict__ Wk, const float* __restrict__ Wv,
    const float* __restrict__ qbuf,
    float* __restrict__ U, float* __restrict__ S) {
  __shared__ __align__(16) float ldsf[24576];
  float* xs = ldsf;
  float* kf = ldsf + 8192;
  float* vf = ldsf + 16384;
  float* qs    = ldsf;
  float* redS  = ldsf + 2048;
  float* sredS = ldsf + 4096;

  int b = blockIdx.y, chunk = blockIdx.x;
  int t = threadIdx.x;
  int wave = t >> 6, lane = t & 63;
  long row0 = (long)b * N_ + (long)chunk * 32;

  for (int j = 0; j < 8; ++j) {
    int r = wave * 8 + j;
    const float4* rp = (const float4*)(in + (row0 + r) * D_);
    float4 v = rp[lane];
    float s = v.x + v.y + v.z + v.w;
    float s2 = v.x * v.x + v.y * v.y + v.z * v.z + v.w * v.w;
#pragma unroll
    for (int off = 32; off; off >>= 1) { s += __shfl_xor(s, off); s2 += __shfl_xor(s2, off); }
    float m = s * (1.0f / 256.0f);
    float var = s2 * (1.0f / 256.0f) - m * m;
    float rstd = rsqrtf(var + 1e-5f);
    int c = lane * 4;
    xs[r * 256 + c + 0] = (v.x - m) * rstd * ln_w[c + 0] + ln_b[c + 0];
    xs[r * 256 + c + 1] = (v.y - m) * rstd * ln_w[c + 1] + ln_b[c + 1];
    xs[r * 256 + c + 2] = (v.z - m) * rstd * ln_w[c + 2] + ln_b[c + 2];
    xs[r * 256 + c + 3] = (v.w - m) * rstd * ln_w[c + 3] + ln_b[c + 3];
  }
  __syncthreads();

  {
    int tx = t & 31, ty = t >> 5;
    const float* W = (tx < 16) ? Wk : Wv;
    float* obf = (tx < 16) ? kf : vf;
    int col0 = (tx & 15) * 16;
    float acc2[4][16];
#pragma unroll
    for (int r = 0; r < 4; ++r)
#pragma unroll
      for (int c = 0; c < 16; ++c) acc2[r][c] = 0.0f;

    for (int k = 0; k < 256; ++k) {
      const float4* wp = (const float4*)(W + k * 256 + col0);
      float4 w0 = wp[0], w1 = wp[1], w2 = wp[2], w3 = wp[3];
#pragma unroll
      for (int r = 0; r < 4; ++r) {
        float x = xs[(ty * 4 + r) * 256 + k];
        acc2[r][0]  += x * w0.x; acc2[r][1]  += x * w0.y; acc2[r][2]  += x * w0.z; acc2[r][3]  += x * w0.w;
        acc2[r][4]  += x * w1.x; acc2[r][5]  += x * w1.y; acc2[r][6]  += x * w1.z; acc2[r][7]  += x * w1.w;
        acc2[r][8]  += x * w2.x; acc2[r][9]  += x * w2.y; acc2[r][10] += x * w2.z; acc2[r][11] += x * w2.w;
        acc2[r][12] += x * w3.x; acc2[r][13] += x * w3.y; acc2[r][14] += x * w3.z; acc2[r][15] += x * w3.w;
      }
    }
#pragma unroll
    for (int r = 0; r < 4; ++r) {
      float4* dst = (float4*)&obf[(ty * 4 + r) * 256 + col0];
      dst[0] = make_float4(acc2[r][0],  acc2[r][1],  acc2[r][2],  acc2[r][3]);
      dst[1] = make_float4(acc2[r][4],  acc2[r][5],  acc2[r][6],  acc2[r][7]);
      dst[2] = make_float4(acc2[r][8],  acc2[r][9],  acc2[r][10], acc2[r][11]);
      dst[3] = make_float4(acc2[r][12], acc2[r][13], acc2[r][14], acc2[r][15]);
    }
  }
  __syncthreads();

#pragma unroll
  for (int i = 0; i < 8; ++i) qs[i * 256 + t] = qbuf[((long)b * 8 + i) * 256 + t];
  for (int e = t; e < 2048; e += 256) redS[e] = 0.0f;
  if (t < 32) sredS[t] = 0.0f;
  __syncthreads();

  float qv[8][4];
#pragma unroll
  for (int i = 0; i < 8; ++i) {
    float4 qq = *(const float4*)&qs[i * 256 + lane * 4];
    qv[i][0] = qq.x; qv[i][1] = qq.y; qv[i][2] = qq.z; qv[i][3] = qq.w;
  }
  float acc[8][4];
  float sacc[8];
#pragma unroll
  for (int i = 0; i < 8; ++i) {
    sacc[i] = 0.0f;
    acc[i][0] = acc[i][1] = acc[i][2] = acc[i][3] = 0.0f;
  }

  for (int jj = wave; jj < 32; jj += 4) {
    float4 k4 = *(const float4*)&kf[jj * 256 + lane * 4];
    float d[8];
#pragma unroll
    for (int i = 0; i < 8; ++i)
      d[i] = qv[i][0] * k4.x + qv[i][1] * k4.y + qv[i][2] * k4.z + qv[i][3] * k4.w;
#pragma unroll
    for (int off2 = 1; off2 < 16; off2 <<= 1) {
#pragma unroll
      for (int i = 0; i < 8; ++i) d[i] += __shfl_xor(d[i], off2);
    }
    float mx = d[0];
#pragma unroll
    for (int i = 1; i < 8; ++i) mx = fmaxf(mx, d[i]);
    float e[8], sum = 0.0f;
#pragma unroll
    for (int i = 0; i < 8; ++i) { e[i] = expf(d[i] - mx); sum += e[i]; }
    float inv = 1.0f / sum;

    float4 v4 = *(const float4*)&vf[jj * 256 + lane * 4];
#pragma unroll
    for (int i = 0; i < 8; ++i) {
      float a = e[i] * inv + EPS_;
      sacc[i] += a;
      acc[i][0] += a * v4.x; acc[i][1] += a * v4.y; acc[i][2] += a * v4.z; acc[i][3] += a * v4.w;
    }
  }

#pragma unroll
  for (int i = 0; i < 8; ++i) {
    atomicAdd(&redS[i * 256 + lane * 4 + 0], acc[i][0]);
    atomicAdd(&redS[i * 256 + lane * 4 + 1], acc[i][1]);
    atomicAdd(&redS[i * 256 + lane * 4 + 2], acc[i][2]);
    atomicAdd(&redS[i * 256 + lane * 4 + 3], acc[i][3]);
  }
  if ((lane & 15) == 0) {
    int h = lane >> 4;
#pragma unroll
    for (int i = 0; i < 8; ++i) atomicAdd(&sredS[i * 4 + h], sacc[i]);
  }
  __syncthreads();

  for (int e = t; e < 2048; e += 256)
    atomicAdd(&U[((long)b * 8 + (e >> 8)) * 256 + (e & 255)], redS[e]);
  if (t < 32) atomicAdd(&S[b * 32 + t], sredS[t]);
}

// ---------- launch ----------
extern "C" void kernel_launch(void* const* d_in, const int* in_sizes, int n_in,
                              void* d_out, int out_size, void* d_ws, size_t ws_size,
                              hipStream_t stream) {
  (void)in_sizes; (void)n_in; (void)out_size;
  const float* inputs        = (const float*)d_in[0];
  const float* slots_mu      = (const float*)d_in[1];
  const float* slots_logsig  = (const float*)d_in[2];
  const float* ln_in_w       = (const float*)d_in[3];
  const float* ln_in_b       = (const float*)d_in[4];
  const float* ln_s_w        = (const float*)d_in[5];
  const float* ln_s_b        = (const float*)d_in[6];
  const float* Wq            = (const float*)d_in[7];
  const float* Wk            = (const float*)d_in[8];
  const float* Wv            = (const float*)d_in[9];
  const float* Wc            = (const float*)d_in[10];
  const float* w_ih          = (const float*)d_in[11];
  const float* w_hh          = (const float*)d_in[12];
  const float* b_ih          = (const float*)d_in[13];
  const float* b_hh          = (const float*)d_in[14];
  const float* ln_m_w        = (const float*)d_in[15];
  const float* ln_m_b        = (const float*)d_in[16];
  const float* w1            = (const float*)d_in[17];
  const float* b1            = (const float*)d_in[18];
  const float* w2            = (const float*)d_in[19];
  const float* b2            = (const float*)d_in[20];

  const size_t KV_BYTES = 2ull * 32 * 4096 * 256 * sizeof(u16);  // 128 MiB
  char* ws = (char*)d_ws;

  if (ws_size >= KV_BYTES + (12ull << 20)) {
    // ---- full fast path: MFMA proj (K + V^T) + MFMA attention ----
    u16* kbuf    = (u16*)ws;                              // 64 MB, row-major K
    u16* Vt      = (u16*)(ws + KV_BYTES / 2);             // 64 MB, V transposed [b][dh][tok]
    char* base   = ws + KV_BYTES;
    float* slots = (float*)base;                          // 256 KB
    float* qbuf  = (float*)(base + (256ull << 10));       // 256 KB
    u16*   Wt2   = (u16*)(base + (256ull << 10));         // 256 KB, aliases qbuf (dead before qproj)
    float* P     = (float*)(base + (512ull << 10));       // 8 MB
    float* Sp    = (float*)(base + (512ull << 10) + (8ull << 20));                       // 128 KB
    float* wTih  = (float*)(base + (512ull << 10) + (8ull << 20) + (128ull << 10));      // 768 KB
    float* wThh  = (float*)(base + (512ull << 10) + (8ull << 20) + (128ull << 10) + (768ull << 10)); // 768 KB

    k_slots_init<<<256, 256, 0, stream>>>(slots_mu, slots_logsig, slots);
    k_gru_t<<<dim3(8, 24), 256, 0, stream>>>(w_ih, wTih);
    k_gru_t<<<dim3(8, 24), 256, 0, stream>>>(w_hh, wThh);
    k_wt2<<<dim3(16, 2, 8), 64, 0, stream>>>(Wk, Wv, Wt2);
    k_proj_mfma4<<<2048, 512, 0, stream>>>(inputs, ln_in_w, ln_in_b, Wt2, kbuf, Vt);

    for (int it = 0; it < 3; ++it) {
      k_qproj2<<<dim3(256, 4), 256, 0, stream>>>(slots, ln_s_w, ln_s_b, Wq, qbuf);
      k_attn4<<<dim3(32, 32), 256, 0, stream>>>(qbuf, kbuf, Vt, P, Sp);
      k_slot_update3<<<256, 768, 0, stream>>>(P, Sp, slots, Wc, wTih, wThh, b_ih, b_hh,
                                              ln_m_w, ln_m_b, w1, b1, w2, b2,
                                              (float*)d_out, it == 2 ? 1 : 0);
    }
  } else if (ws_size >= KV_BYTES + (1ull << 20)) {
    // ---- mid tier (round-2 structure) ----
    u16* kbuf    = (u16*)ws;
    u16* vbuf    = (u16*)(ws + KV_BYTES / 2);
    char* base   = ws + KV_BYTES;
    float* slots = (float*)base;                          // 256 KB
    float* qbuf  = (float*)(base + 262144);               // 256 KB
    float* U     = (float*)(base + 524288);               // 256 KB
    float* S     = (float*)(base + 786432);               // 4 KB
    u16* Wt      = (u16*)(base + 262144);                 // aliases qbuf

    k_slots_init<<<256, 256, 0, stream>>>(slots_mu, slots_logsig, slots);
    k_wt<<<dim3(256, 2), 256, 0, stream>>>(Wk, Wv, Wt);
    k_proj_mfma2<<<dim3(2048, 2), 512, 0, stream>>>(inputs, ln_in_w, ln_in_b, Wt, kbuf, vbuf);

    for (int it = 0; it < 3; ++it) {
      hipMemsetAsync(U, 0, (65536 + 1024) * sizeof(float), stream);
      k_qproj<<<256, 256, 0, stream>>>(slots, ln_s_w, ln_s_b, Wq, qbuf);
      k_attn<<<dim3(32, 32), 256, 0, stream>>>(qbuf, kbuf, vbuf, U, S);
      k_slot_update<<<256, 256, 0, stream>>>(U, S, slots, Wc, w_ih, w_hh, b_ih, b_hh,
                                             ln_m_w, ln_m_b, w1, b1, w2, b2,
                                             (float*)d_out, it == 2 ? 1 : 0);
    }
  } else {
    // ---- fallback ----
    float* slots = (float*)ws;                 // 256 KB
    float* qbuf  = (float*)(ws + 262144);      // 256 KB
    float* U     = (float*)(ws + 524288);      // 256 KB
    float* S     = (float*)(ws + 786432);      // 4 KB

    k_slots_init<<<256, 256, 0, stream>>>(slots_mu, slots_logsig, slots);
    for (int it = 0; it < 3; ++it) {
      hipMemsetAsync(U, 0, (65536 + 1024) * sizeof(float), stream);
      k_qproj<<<256, 256, 0, stream>>>(slots, ln_s_w, ln_s_b, Wq, qbuf);
      k_fused_attn<<<dim3(128, 32), 256, 0, stream>>>(inputs, ln_in_w, ln_in_b,
                                                      Wk, Wv, qbuf, U, S);
      k_slot_update<<<256, 256, 0, stream>>>(U, S, slots, Wc, w_ih, w_hh, b_ih, b_hh,
                                             ln_m_w, ln_m_b, w1, b1, w2, b2,
                                             (float*)d_out, it == 2 ? 1 : 0);
    }
  }
}